// Round 1
// baseline (773.241 us; speedup 1.0000x reference)
//
#include <hip/hip_runtime.h>
#include <math.h>

#define Bn   64
#define Ln   4096
#define LQn  128
#define Dn   32
#define ETn  128
#define Hn   128
#define G3n  384
#define NDEG 12

typedef __attribute__((ext_vector_type(2))) float f32x2;

// ---- workspace layout (float offsets) ----
#define WS_C    0                          // 128*12
#define WS_ATT  4096                       // 64*128*128 = 1048576
#define WS_G0   (WS_ATT + Bn*LQn*Hn)       // 64*128*256 = 2097152
#define WS_CLS  (WS_G0 + Bn*LQn*2*Hn)      // 64*256
#define WS_GI   (WS_CLS + Bn*2*Hn)         // 8192*768 = 6291456

// =================== K1: per-query score-polynomial coefficients ===================
// scores[b,q,l] = sum_d C[q,d] * t^d,  t = time_steps[b,l]
__global__ __launch_bounds__(128) void k_coeff(
    const float* __restrict__ qtimes, const float* __restrict__ lin_w,
    const float* __restrict__ lin_b, const float* __restrict__ per_w,
    const float* __restrict__ per_b, const float* __restrict__ wq,
    const float* __restrict__ bq, const float* __restrict__ wk,
    const float* __restrict__ bk, float* __restrict__ C)
{
    __shared__ float qe[ETn], qp[ETn], qt[ETn];
    const int q = blockIdx.x, tid = threadIdx.x;
    const float t = qtimes[q];
    const float lw = lin_w[0], lb = lin_b[0];
    qe[tid] = (tid == 0) ? (t * lw + lb) : sinf(t * per_w[tid - 1] + per_b[tid - 1]);
    __syncthreads();
    {   // qp[e] = sum_i qe[i]*wq[i][e] + bq[e]
        float a = bq[tid];
        for (int i = 0; i < ETn; ++i) a += qe[i] * wq[i * ETn + tid];
        qp[tid] = a;
    }
    __syncthreads();
    {   // qt[c] = sum_e qp[e]*wk[c][e]
        float a = 0.f;
        for (int e = 0; e < ETn; ++e) a += qp[e] * wk[tid * ETn + e];
        qt[tid] = a;
    }
    __syncthreads();
    if (tid < NDEG) {
        const int d = tid;
        float Cd = 0.f;
        for (int j = 0; j < ETn - 1; ++j) {
            float w = per_w[j], bb = per_b[j];
            float sb = sinf(bb), cb = cosf(bb);
            float sd = ((d & 3) == 0) ? sb : ((d & 3) == 1) ? cb : ((d & 3) == 2) ? -sb : -cb;
            float wp = 1.f;
            for (int u = 1; u <= d; ++u) wp *= w / (float)u;   // w^d / d!
            Cd += qt[j + 1] * wp * sd;
        }
        if (d == 0) {
            float qb = 0.f;
            for (int e = 0; e < ETn; ++e) qb += qp[e] * bk[e];
            Cd += qt[0] * lb + qb;
        }
        if (d == 1) Cd += qt[0] * lw;
        C[q * NDEG + d] = Cd * 0.08838834764831845f;   // 1/sqrt(128)
    }
}

// =================== K2: fused flash attention + wo projection ===================
// grid: 256 blocks = (b, qgroup of 32), 256 threads: thread = (q_local = tid>>3, i = tid&7)
#define TLn 128
__global__ __launch_bounds__(256) void k_attn(
    const float* __restrict__ x, const float* __restrict__ tsteps,
    const float* __restrict__ Cc, const float* __restrict__ wo,
    const float* __restrict__ bo, float* __restrict__ att_out)
{
    __shared__ float4 x_l[TLn * 8];        // [l][8] float4 == x[l][0..31]
    __shared__ float  t_l[TLn];
    __shared__ float  wo_l[Dn * ETn];      // 32 x 128
    __shared__ float  att_l[32 * 36];      // padded

    const int tid = threadIdx.x;
    const int b = blockIdx.x >> 2, qg = blockIdx.x & 3;
    const int ql = tid >> 3;               // 0..31
    const int q  = qg * 32 + ql;
    const int i  = tid & 7;
    const int lane = tid & 63;
    const int basesrc = lane & 56;

    float c[NDEG];
#pragma unroll
    for (int d = 0; d < NDEG; ++d) c[d] = Cc[q * NDEG + d];
    for (int u = tid; u < Dn * ETn; u += 256) wo_l[u] = wo[u];

    const float4* xg = (const float4*)(x + (size_t)b * Ln * Dn);
    const float*  tg = tsteps + (size_t)b * Ln;

    float4 xr[4];
    float  tr = 0.f;
#pragma unroll
    for (int w = 0; w < 4; ++w) xr[w] = xg[tid + w * 256];
    if (tid < TLn) tr = tg[tid];

    float m_run = -1e30f, s_run = 0.f;
    float acc0 = 0.f, acc1 = 0.f, acc2 = 0.f, acc3 = 0.f;
    const int NT = Ln / TLn;   // 32

    for (int ti = 0; ti < NT; ++ti) {
        __syncthreads();
#pragma unroll
        for (int w = 0; w < 4; ++w) x_l[tid + w * 256] = xr[w];
        if (tid < TLn) t_l[tid] = tr;
        __syncthreads();
        if (ti + 1 < NT) {
            const int off = (ti + 1) * TLn;
#pragma unroll
            for (int w = 0; w < 4; ++w) xr[w] = xg[off * 8 + tid + w * 256];
            if (tid < TLn) tr = tg[off + tid];
        }
        // ---- scores (Horner) for l = 8k+i ----
        float p[16];
        float mloc = -1e30f;
#pragma unroll
        for (int k = 0; k < 16; ++k) {
            float t = t_l[8 * k + i];
            float s = c[NDEG - 1];
#pragma unroll
            for (int d = NDEG - 2; d >= 0; --d) s = s * t + c[d];
            p[k] = s;
            mloc = fmaxf(mloc, s);
        }
        mloc = fmaxf(mloc, __shfl_xor(mloc, 1));
        mloc = fmaxf(mloc, __shfl_xor(mloc, 2));
        mloc = fmaxf(mloc, __shfl_xor(mloc, 4));
        const float m_new = fmaxf(m_run, mloc);
        float psum = 0.f;
#pragma unroll
        for (int k = 0; k < 16; ++k) { p[k] = __expf(p[k] - m_new); psum += p[k]; }
        psum += __shfl_xor(psum, 1);
        psum += __shfl_xor(psum, 2);
        psum += __shfl_xor(psum, 4);
        const float scale = __expf(m_run - m_new);
        s_run = s_run * scale + psum;
        acc0 *= scale; acc1 *= scale; acc2 *= scale; acc3 *= scale;
        m_run = m_new;
        // ---- att accumulation: acc[d] += p[l] * x[l][4i..4i+3] ----
#pragma unroll
        for (int k = 0; k < 16; ++k) {
#pragma unroll
            for (int j = 0; j < 8; ++j) {
                float  pv = __shfl(p[k], basesrc | j);
                float4 xv = x_l[(8 * k + j) * 8 + i];
                acc0 += pv * xv.x; acc1 += pv * xv.y; acc2 += pv * xv.z; acc3 += pv * xv.w;
            }
        }
    }
    const float inv = 1.f / s_run;
    __syncthreads();
    att_l[ql * 36 + 4 * i + 0] = acc0 * inv;
    att_l[ql * 36 + 4 * i + 1] = acc1 * inv;
    att_l[ql * 36 + 4 * i + 2] = acc2 * inv;
    att_l[ql * 36 + 4 * i + 3] = acc3 * inv;
    __syncthreads();
    // ---- att_out[q][h] = att[q]·wo[:,h] + bo[h] ----
#pragma unroll
    for (int r4 = 0; r4 < 4; ++r4) {
        float4 o4;
        float* po = &o4.x;
#pragma unroll
        for (int rr = 0; rr < 4; ++rr) {
            const int h = i * 16 + r4 * 4 + rr;
            float a = bo[h];
            for (int d = 0; d < Dn; ++d) a += att_l[ql * 36 + d] * wo_l[d * ETn + h];
            po[rr] = a;
        }
        *(float4*)&att_out[((size_t)(b * LQn + q)) * Hn + i * 16 + r4 * 4] = o4;
    }
}

// =================== K3: tiled f32 GEMM  C[M,N] = A(MxK) @ B(NxK)^T + bias ===================
__global__ __launch_bounds__(256) void k_gemm_nt(
    const float* __restrict__ A, const float* __restrict__ Bm,
    const float* __restrict__ bias, float* __restrict__ Cm,
    int M, int N, int K)
{
    __shared__ float4 A_l[64 * 16];
    __shared__ float4 B_l[64 * 16];
    const int tid = threadIdx.x;
    const int m0 = blockIdx.x * 64, n0 = blockIdx.y * 64;
    const int r0 = (tid >> 4) << 2, c0 = (tid & 15) << 2;
    const int K4 = K >> 2;
    float acc[4][4] = {};
    const float4* Ag = (const float4*)A;
    const float4* Bg = (const float4*)Bm;

    for (int k0 = 0; k0 < K; k0 += 64) {
        __syncthreads();
#pragma unroll
        for (int w = 0; w < 4; ++w) {
            const int idx = tid + w * 256;         // 0..1023
            const int row = idx >> 4, c4 = idx & 15;
            const int sc = c4 ^ ((row >> 2) & 7);  // XOR swizzle (16B chunks)
            A_l[row * 16 + sc] = Ag[(size_t)(m0 + row) * K4 + (k0 >> 2) + c4];
            B_l[row * 16 + sc] = Bg[(size_t)(n0 + row) * K4 + (k0 >> 2) + c4];
        }
        __syncthreads();
#pragma unroll
        for (int k4 = 0; k4 < 16; ++k4) {
            float4 av[4], bv[4];
#pragma unroll
            for (int j = 0; j < 4; ++j) av[j] = A_l[(r0 + j) * 16 + (k4 ^ (((r0 + j) >> 2) & 7))];
#pragma unroll
            for (int j = 0; j < 4; ++j) bv[j] = B_l[(c0 + j) * 16 + (k4 ^ (((c0 + j) >> 2) & 7))];
#pragma unroll
            for (int ri = 0; ri < 4; ++ri)
#pragma unroll
                for (int ci = 0; ci < 4; ++ci)
                    acc[ri][ci] += av[ri].x * bv[ci].x + av[ri].y * bv[ci].y
                                 + av[ri].z * bv[ci].z + av[ri].w * bv[ci].w;
        }
    }
#pragma unroll
    for (int ri = 0; ri < 4; ++ri) {
        float4 o4;
        o4.x = acc[ri][0] + bias[n0 + c0 + 0];
        o4.y = acc[ri][1] + bias[n0 + c0 + 1];
        o4.z = acc[ri][2] + bias[n0 + c0 + 2];
        o4.w = acc[ri][3] + bias[n0 + c0 + 3];
        *(float4*)&Cm[(size_t)(m0 + r0 + ri) * N + n0 + c0] = o4;
    }
}

// =================== K4: GRU recurrence (one block per (b, dir)) ===================
// 768 threads: thread = (o = tid>>1, half = tid&1); whh row held in registers.
__global__ __launch_bounds__(768) void k_gru(
    const float* __restrict__ gi, const float* __restrict__ whh,
    const float* __restrict__ bhh, float* __restrict__ seq_out,
    float* __restrict__ final_out)
{
    __shared__ float h_l[Hn];
    __shared__ float gh_l[G3n];
    __shared__ float gi_l[G3n];
    const int tid = threadIdx.x;
    const int b = blockIdx.x >> 1, dir = blockIdx.x & 1;
    const int o = tid >> 1, half = tid & 1;

    f32x2 wr[32];
    const float* wrow = whh + ((size_t)dir * G3n + o) * Hn + half * 64;
#pragma unroll
    for (int k = 0; k < 32; ++k) wr[k] = ((const f32x2*)wrow)[k];
    const float bh = bhh[dir * G3n + o];
    if (tid < Hn) h_l[tid] = 0.f;
    __syncthreads();

    const float* gib = gi + ((size_t)b * LQn) * 768 + dir * G3n;
    for (int step = 0; step < LQn; ++step) {
        const int l = dir ? (LQn - 1 - step) : step;
        const float gval = gib[(size_t)l * 768 + o];
        f32x2 a2 = {0.f, 0.f}, b2 = {0.f, 0.f};
        const float4* hp4 = (const float4*)(h_l + half * 64);
#pragma unroll
        for (int k = 0; k < 16; ++k) {
            float4 hv = hp4[k];
            f32x2 h01; h01.x = hv.x; h01.y = hv.y;
            f32x2 h23; h23.x = hv.z; h23.y = hv.w;
            asm("v_pk_fma_f32 %0, %1, %2, %0" : "+v"(a2) : "v"(wr[2 * k]),     "v"(h01));
            asm("v_pk_fma_f32 %0, %1, %2, %0" : "+v"(b2) : "v"(wr[2 * k + 1]), "v"(h23));
        }
        float acc = a2.x + a2.y + b2.x + b2.y;
        acc += __shfl_xor(acc, 1);
        acc += bh;
        gh_l[o] = acc;     // both halves write the same value (benign)
        gi_l[o] = gval;
        __syncthreads();
        if (tid < Hn) {
            const int j = tid;
            const float r = 1.f / (1.f + __expf(-(gi_l[j]       + gh_l[j])));
            const float z = 1.f / (1.f + __expf(-(gi_l[j + 128] + gh_l[j + 128])));
            const float n = tanhf(gi_l[j + 256] + r * gh_l[j + 256]);
            const float hn = (1.f - z) * n + z * h_l[j];
            h_l[j] = hn;
            if (seq_out) seq_out[((size_t)(b * LQn + l)) * (2 * Hn) + dir * Hn + j] = hn;
        }
        __syncthreads();
    }
    if (final_out && tid < Hn) final_out[b * 2 * Hn + dir * Hn + tid] = h_l[tid];
}

// =================== K5: classifier MLP ===================
__global__ __launch_bounds__(256) void k_cls(
    const float* __restrict__ cls_in,
    const float* __restrict__ c1w, const float* __restrict__ c1b,
    const float* __restrict__ c2w, const float* __restrict__ c2b,
    const float* __restrict__ c3w, const float* __restrict__ c3b,
    float* __restrict__ out)
{
    __shared__ float ci[256], y1[128], y2[64];
    const int b = blockIdx.x, tid = threadIdx.x;
    ci[tid] = cls_in[b * 256 + tid];
    __syncthreads();
    if (tid < 128) { float a = c1b[tid]; for (int i = 0; i < 256; ++i) a += ci[i] * c1w[i * 128 + tid]; y1[tid] = a; }
    __syncthreads();
    if (tid < 64)  { float a = c2b[tid]; for (int i = 0; i < 128; ++i) a += y1[i] * c2w[i * 64 + tid];  y2[tid] = a; }
    __syncthreads();
    if (tid < 6)   { float a = c3b[tid]; for (int i = 0; i < 64; ++i)  a += y2[i] * c3w[i * 6 + tid];   out[b * 6 + tid] = a; }
}

// =================== launch ===================
extern "C" void kernel_launch(void* const* d_in, const int* in_sizes, int n_in,
                              void* d_out, int out_size, void* d_ws, size_t ws_size,
                              hipStream_t stream)
{
    const float* x        = (const float*)d_in[0];
    const float* tsteps   = (const float*)d_in[1];
    const float* qtimes   = (const float*)d_in[2];
    const float* lin_w    = (const float*)d_in[3];
    const float* lin_b    = (const float*)d_in[4];
    const float* per_w    = (const float*)d_in[5];
    const float* per_b    = (const float*)d_in[6];
    const float* wq       = (const float*)d_in[7];
    const float* bq       = (const float*)d_in[8];
    const float* wk       = (const float*)d_in[9];
    const float* bk       = (const float*)d_in[10];
    const float* wo       = (const float*)d_in[11];
    const float* bo       = (const float*)d_in[12];
    const float* g0_wih   = (const float*)d_in[13];
    const float* g0_whh   = (const float*)d_in[14];
    const float* g0_bih   = (const float*)d_in[15];
    const float* g0_bhh   = (const float*)d_in[16];
    const float* g1_wih   = (const float*)d_in[17];
    const float* g1_whh   = (const float*)d_in[18];
    const float* g1_bih   = (const float*)d_in[19];
    const float* g1_bhh   = (const float*)d_in[20];
    const float* c1w      = (const float*)d_in[21];
    const float* c1b      = (const float*)d_in[22];
    const float* c2w      = (const float*)d_in[23];
    const float* c2b      = (const float*)d_in[24];
    const float* c3w      = (const float*)d_in[25];
    const float* c3b      = (const float*)d_in[26];
    float* out = (float*)d_out;
    float* ws  = (float*)d_ws;

    float* Cws   = ws + WS_C;
    float* attO  = ws + WS_ATT;
    float* g0buf = ws + WS_G0;
    float* clsin = ws + WS_CLS;
    float* gibuf = ws + WS_GI;

    k_coeff<<<128, 128, 0, stream>>>(qtimes, lin_w, lin_b, per_w, per_b, wq, bq, wk, bk, Cws);
    k_attn<<<256, 256, 0, stream>>>(x, tsteps, Cws, wo, bo, attO);

    // layer 0: gi = att_out @ wih^T + bih   (A: 8192x128, B: 768x128)
    k_gemm_nt<<<dim3(128, 12), 256, 0, stream>>>(attO, g0_wih, g0_bih, gibuf, Bn * LQn, 768, 128);
    k_gru<<<128, 768, 0, stream>>>(gibuf, g0_whh, g0_bhh, g0buf, nullptr);

    // layer 1: gi = g0 @ wih^T + bih        (A: 8192x256, B: 768x256)
    k_gemm_nt<<<dim3(128, 12), 256, 0, stream>>>(g0buf, g1_wih, g1_bih, gibuf, Bn * LQn, 768, 256);
    k_gru<<<128, 768, 0, stream>>>(gibuf, g1_whh, g1_bhh, nullptr, clsin);

    k_cls<<<64, 256, 0, stream>>>(clsin, c1w, c1b, c2w, c2b, c3w, c3b, out);
}

// Round 2
// 624.922 us; speedup vs baseline: 1.2373x; 1.2373x over previous
//
#include <hip/hip_runtime.h>
#include <math.h>

#define Bn   64
#define Ln   4096
#define LQn  128
#define Dn   32
#define ETn  128
#define Hn   128
#define G3n  384
#define NDEG 12
#define TLn  128

typedef __attribute__((ext_vector_type(2))) float f32x2;

// DPP helpers (VALU cross-lane, no LDS pipe)
#define DPPF(x, ctrl) __int_as_float(__builtin_amdgcn_update_dpp(0, __float_as_int(x), (ctrl), 0xF, 0xF, true))
#define QP_XOR1 0xB1   // quad_perm [1,0,3,2]
#define QP_XOR2 0x4E   // quad_perm [2,3,0,1]
#define QP_B0   0x00   // quad_perm [0,0,0,0]
#define QP_B1   0x55   // quad_perm [1,1,1,1]
#define QP_B2   0xAA   // quad_perm [2,2,2,2]
#define ROW_HALF_MIRROR 0x141

// ---- workspace layout (float offsets) ----
#define WS_C    0                          // 128*12
#define WS_ATT  4096                       // 8192*32 = 262144
#define WS_WT   (WS_ATT + Bn*LQn*Dn)       // 768*32 = 24576
#define WS_B2   (WS_WT + 768*32)           // 768 (pad to 1024)
#define WS_CLS  (WS_B2 + 1024)             // 64*256
#define WS_G0   (WS_CLS + Bn*2*Hn)         // 8192*256
#define WS_GI   (WS_G0 + Bn*LQn*2*Hn)      // 8192*768

// =================== K1: per-query score-polynomial coefficients ===================
__global__ __launch_bounds__(128) void k_coeff(
    const float* __restrict__ qtimes, const float* __restrict__ lin_w,
    const float* __restrict__ lin_b, const float* __restrict__ per_w,
    const float* __restrict__ per_b, const float* __restrict__ wq,
    const float* __restrict__ bq, const float* __restrict__ wk,
    const float* __restrict__ bk, float* __restrict__ C)
{
    __shared__ float qe[ETn], qp[ETn], qt[ETn];
    const int q = blockIdx.x, tid = threadIdx.x;
    const float t = qtimes[q];
    const float lw = lin_w[0], lb = lin_b[0];
    qe[tid] = (tid == 0) ? (t * lw + lb) : sinf(t * per_w[tid - 1] + per_b[tid - 1]);
    __syncthreads();
    {
        float a = bq[tid];
        for (int i = 0; i < ETn; ++i) a += qe[i] * wq[i * ETn + tid];
        qp[tid] = a;
    }
    __syncthreads();
    {
        float a = 0.f;
        for (int e = 0; e < ETn; ++e) a += qp[e] * wk[tid * ETn + e];
        qt[tid] = a;
    }
    __syncthreads();
    if (tid < NDEG) {
        const int d = tid;
        float Cd = 0.f;
        for (int j = 0; j < ETn - 1; ++j) {
            float w = per_w[j], bb = per_b[j];
            float sb = sinf(bb), cb = cosf(bb);
            float sd = ((d & 3) == 0) ? sb : ((d & 3) == 1) ? cb : ((d & 3) == 2) ? -sb : -cb;
            float wp = 1.f;
            for (int u = 1; u <= d; ++u) wp *= w / (float)u;   // w^d / d!
            Cd += qt[j + 1] * wp * sd;
        }
        if (d == 0) {
            float qb = 0.f;
            for (int e = 0; e < ETn; ++e) qb += qp[e] * bk[e];
            Cd += qt[0] * lb + qb;
        }
        if (d == 1) Cd += qt[0] * lw;
        C[q * NDEG + d] = Cd * 0.08838834764831845f;   // 1/sqrt(128)
    }
}

// =================== K1b: fold wo (+bo) into layer-0 wih ===================
// Wt[o][d] = sum_h wih[o][h]*wo[d][h];  bias2[o] = sum_h bo[h]*wih[o][h] + bih[o]
__global__ __launch_bounds__(256) void k_fuse(
    const float* __restrict__ wih, const float* __restrict__ wo,
    const float* __restrict__ bo, const float* __restrict__ bih,
    float* __restrict__ Wt, float* __restrict__ bias2)
{
    const int t = blockIdx.x * 256 + threadIdx.x;
    if (t < 768 * 32) {
        const int o = t >> 5, d = t & 31;
        const float* wr = wih + (size_t)o * 128;
        const float* wc = wo + (size_t)d * 128;
        float a = 0.f;
        for (int h = 0; h < 128; ++h) a += wr[h] * wc[h];
        Wt[t] = a;
    } else if (t < 768 * 33) {
        const int o = t - 768 * 32;
        const float* wr = wih + (size_t)o * 128;
        float a = bih[o];
        for (int h = 0; h < 128; ++h) a += bo[h] * wr[h];
        bias2[o] = a;
    }
}

// =================== K2: fused flash attention -> raw att (8192 x 32) ===================
// grid: 256 = (b, qgroup of 32); 256 threads: (ql = tid>>3, i = tid&7)
// lane accumulates ALL 32 d for its own l-subset (l = 8k+i); 8-lane reduce once at end.
__global__ __launch_bounds__(256) void k_attn(
    const float* __restrict__ x, const float* __restrict__ tsteps,
    const float* __restrict__ Cc, float* __restrict__ att)
{
    __shared__ float4 x_l[TLn * 8];        // [l][8] float4 == x[l][0..31]
    __shared__ float  t_l[TLn];

    const int tid = threadIdx.x;
    const int b = blockIdx.x >> 2, qg = blockIdx.x & 3;
    const int ql = tid >> 3;
    const int q  = qg * 32 + ql;
    const int i  = tid & 7;

    float c[NDEG];
#pragma unroll
    for (int d = 0; d < NDEG; ++d) c[d] = Cc[q * NDEG + d];

    const float4* xg = (const float4*)(x + (size_t)b * Ln * Dn);
    const float*  tg = tsteps + (size_t)b * Ln;

    float4 xr[4];
    float  tr = 0.f;
#pragma unroll
    for (int w = 0; w < 4; ++w) xr[w] = xg[tid + w * 256];
    if (tid < TLn) tr = tg[tid];

    float m_run = -1e30f, s_run = 0.f;
    float4 acc4[8];
#pragma unroll
    for (int u = 0; u < 8; ++u) { acc4[u].x = 0.f; acc4[u].y = 0.f; acc4[u].z = 0.f; acc4[u].w = 0.f; }

    const int NT = Ln / TLn;   // 32
    for (int ti = 0; ti < NT; ++ti) {
        __syncthreads();
#pragma unroll
        for (int w = 0; w < 4; ++w) x_l[tid + w * 256] = xr[w];
        if (tid < TLn) t_l[tid] = tr;
        __syncthreads();
        if (ti + 1 < NT) {
            const int off = (ti + 1) * TLn;
#pragma unroll
            for (int w = 0; w < 4; ++w) xr[w] = xg[off * 8 + tid + w * 256];
            if (tid < TLn) tr = tg[off + tid];
        }
        // ---- scores (Horner) for own l = 8k+i ----
        float p[16];
        float mloc = -1e30f;
#pragma unroll
        for (int k = 0; k < 16; ++k) {
            float t = t_l[8 * k + i];
            float s = c[NDEG - 1];
#pragma unroll
            for (int d = NDEG - 2; d >= 0; --d) s = s * t + c[d];
            p[k] = s;
            mloc = fmaxf(mloc, s);
        }
        // 8-lane max via DPP (VALU only)
        mloc = fmaxf(mloc, DPPF(mloc, QP_XOR1));
        mloc = fmaxf(mloc, DPPF(mloc, QP_XOR2));
        mloc = fmaxf(mloc, DPPF(mloc, ROW_HALF_MIRROR));
        const float m_new = fmaxf(m_run, mloc);
        const float scale = __expf(m_run - m_new);
        m_run = m_new;
        s_run *= scale;
#pragma unroll
        for (int u = 0; u < 8; ++u) {
            acc4[u].x *= scale; acc4[u].y *= scale; acc4[u].z *= scale; acc4[u].w *= scale;
        }
#pragma unroll
        for (int k = 0; k < 16; ++k) {
            const float pv = __expf(p[k] - m_new);
            s_run += pv;
            const float4* xrow = &x_l[(8 * k + i) * 8];
#pragma unroll
            for (int u = 0; u < 8; ++u) {
                float4 xv = xrow[u];
                acc4[u].x = fmaf(pv, xv.x, acc4[u].x);
                acc4[u].y = fmaf(pv, xv.y, acc4[u].y);
                acc4[u].z = fmaf(pv, xv.z, acc4[u].z);
                acc4[u].w = fmaf(pv, xv.w, acc4[u].w);
            }
        }
    }
    // ---- one-time 8-lane reduction (DPP) ----
#pragma unroll
    for (int rd = 0; rd < 3; ++rd) {
        const int ctrl0 = (rd == 0) ? QP_XOR1 : (rd == 1) ? QP_XOR2 : ROW_HALF_MIRROR;
        if (rd == 0) {
            s_run += DPPF(s_run, QP_XOR1);
#pragma unroll
            for (int u = 0; u < 8; ++u) {
                acc4[u].x += DPPF(acc4[u].x, QP_XOR1); acc4[u].y += DPPF(acc4[u].y, QP_XOR1);
                acc4[u].z += DPPF(acc4[u].z, QP_XOR1); acc4[u].w += DPPF(acc4[u].w, QP_XOR1);
            }
        } else if (rd == 1) {
            s_run += DPPF(s_run, QP_XOR2);
#pragma unroll
            for (int u = 0; u < 8; ++u) {
                acc4[u].x += DPPF(acc4[u].x, QP_XOR2); acc4[u].y += DPPF(acc4[u].y, QP_XOR2);
                acc4[u].z += DPPF(acc4[u].z, QP_XOR2); acc4[u].w += DPPF(acc4[u].w, QP_XOR2);
            }
        } else {
            s_run += DPPF(s_run, ROW_HALF_MIRROR);
#pragma unroll
            for (int u = 0; u < 8; ++u) {
                acc4[u].x += DPPF(acc4[u].x, ROW_HALF_MIRROR); acc4[u].y += DPPF(acc4[u].y, ROW_HALF_MIRROR);
                acc4[u].z += DPPF(acc4[u].z, ROW_HALF_MIRROR); acc4[u].w += DPPF(acc4[u].w, ROW_HALF_MIRROR);
            }
        }
        (void)ctrl0;
    }
    const float inv = 1.f / s_run;
    float4 o4 = acc4[i];
    o4.x *= inv; o4.y *= inv; o4.z *= inv; o4.w *= inv;
    *(float4*)&att[((size_t)(b * LQn + q)) * Dn + 4 * i] = o4;
}

// =================== K3: tiled f32 GEMM  C[M,N] = A(MxK) @ B(NxK)^T + bias, BK=32 ===================
__global__ __launch_bounds__(256) void k_gemm_nt(
    const float* __restrict__ A, const float* __restrict__ Bm,
    const float* __restrict__ bias, float* __restrict__ Cm,
    int N, int K)
{
    __shared__ float4 A_l[64 * 8];
    __shared__ float4 B_l[64 * 8];
    const int tid = threadIdx.x;
    const int m0 = blockIdx.x * 64, n0 = blockIdx.y * 64;
    const int r0 = (tid >> 4) << 2, c0 = (tid & 15) << 2;
    const int K4 = K >> 2;
    float acc[4][4] = {};
    const float4* Ag = (const float4*)A;
    const float4* Bg = (const float4*)Bm;

    for (int k0 = 0; k0 < K4; k0 += 8) {
        __syncthreads();
#pragma unroll
        for (int w = 0; w < 2; ++w) {
            const int idx = tid + w * 256;         // 0..511
            const int row = idx >> 3, c4 = idx & 7;
            const int sc = (c4 + row + (row >> 2)) & 7;   // bank-spreading swizzle
            A_l[row * 8 + sc] = Ag[(size_t)(m0 + row) * K4 + k0 + c4];
            B_l[row * 8 + sc] = Bg[(size_t)(n0 + row) * K4 + k0 + c4];
        }
        __syncthreads();
#pragma unroll
        for (int k4 = 0; k4 < 8; ++k4) {
            float4 av[4], bv[4];
#pragma unroll
            for (int j = 0; j < 4; ++j) {
                const int ra = r0 + j;
                av[j] = A_l[ra * 8 + ((k4 + ra + (ra >> 2)) & 7)];
            }
#pragma unroll
            for (int j = 0; j < 4; ++j) {
                const int rb = c0 + j;
                bv[j] = B_l[rb * 8 + ((k4 + rb + (rb >> 2)) & 7)];
            }
#pragma unroll
            for (int ri = 0; ri < 4; ++ri)
#pragma unroll
                for (int ci = 0; ci < 4; ++ci)
                    acc[ri][ci] += av[ri].x * bv[ci].x + av[ri].y * bv[ci].y
                                 + av[ri].z * bv[ci].z + av[ri].w * bv[ci].w;
        }
    }
#pragma unroll
    for (int ri = 0; ri < 4; ++ri) {
        float4 o4;
        o4.x = acc[ri][0] + bias[n0 + c0 + 0];
        o4.y = acc[ri][1] + bias[n0 + c0 + 1];
        o4.z = acc[ri][2] + bias[n0 + c0 + 2];
        o4.w = acc[ri][3] + bias[n0 + c0 + 3];
        *(float4*)&Cm[(size_t)(m0 + r0 + ri) * N + n0 + c0] = o4;
    }
}

// =================== K4: GRU recurrence — quad-per-unit, DPP combine, 1 barrier/step ===================
// 512 threads: (j = tid>>2 in [0,128), q = tid&3 = 32-wide h-slice). One block per (b,dir).
__global__ __launch_bounds__(512, 2) void k_gru(
    const float* __restrict__ gi, const float* __restrict__ whh,
    const float* __restrict__ bhh, float* __restrict__ seq_out,
    float* __restrict__ final_out)
{
    __shared__ float h_l[2][4 * 36];       // quarter-padded (36) double buffer
    const int tid = threadIdx.x;
    const int b = blockIdx.x >> 1, dir = blockIdx.x & 1;
    const int j = tid >> 2, q = tid & 3;

    // weights: w{r,z,n}[k] = whh[dir][g*128+j][32q + 2k .. +1]
    f32x2 wr[16], wz[16], wn[16];
    {
        const float* wb = whh + ((size_t)dir * G3n + j) * Hn + 32 * q;
        const f32x2* p0 = (const f32x2*)(wb);
        const f32x2* p1 = (const f32x2*)(wb + (size_t)128 * Hn);
        const f32x2* p2 = (const f32x2*)(wb + (size_t)256 * Hn);
#pragma unroll
        for (int k = 0; k < 16; ++k) { wr[k] = p0[k]; wz[k] = p1[k]; wn[k] = p2[k]; }
    }
    const float bhr = bhh[dir * G3n + j];
    const float bhz = bhh[dir * G3n + 128 + j];
    const float bhn = bhh[dir * G3n + 256 + j];

    if (tid < 144) h_l[0][tid] = 0.f;
    __syncthreads();

    const float* gib = gi + (size_t)b * LQn * 768 + dir * G3n;
    const int hslot = (j >> 5) * 36 + (j & 31);

    float gi_nxt = (q < 3) ? gib[(size_t)(dir ? LQn - 1 : 0) * 768 + q * Hn + j] : 0.f;

    int cur = 0;
    for (int step = 0; step < LQn; ++step) {
        const int l = dir ? (LQn - 1 - step) : step;
        const float gi_cur = gi_nxt;
        if (step + 1 < LQn && q < 3) {
            const int ln = dir ? (LQn - 2 - step) : (step + 1);
            gi_nxt = gib[(size_t)ln * 768 + q * Hn + j];
        }
        // ---- 3 gate dots over this thread's 32-slice of h ----
        const float4* hq = (const float4*)(&h_l[cur][q * 36]);
        f32x2 ar = {0.f, 0.f}, az = {0.f, 0.f}, an = {0.f, 0.f};
#pragma unroll
        for (int cc = 0; cc < 8; ++cc) {
            float4 hv = hq[cc];
            f32x2 h01; h01.x = hv.x; h01.y = hv.y;
            f32x2 h23; h23.x = hv.z; h23.y = hv.w;
            asm("v_pk_fma_f32 %0, %1, %2, %0" : "+v"(ar) : "v"(wr[2 * cc]),     "v"(h01));
            asm("v_pk_fma_f32 %0, %1, %2, %0" : "+v"(az) : "v"(wz[2 * cc]),     "v"(h01));
            asm("v_pk_fma_f32 %0, %1, %2, %0" : "+v"(an) : "v"(wn[2 * cc]),     "v"(h01));
            asm("v_pk_fma_f32 %0, %1, %2, %0" : "+v"(ar) : "v"(wr[2 * cc + 1]), "v"(h23));
            asm("v_pk_fma_f32 %0, %1, %2, %0" : "+v"(az) : "v"(wz[2 * cc + 1]), "v"(h23));
            asm("v_pk_fma_f32 %0, %1, %2, %0" : "+v"(an) : "v"(wn[2 * cc + 1]), "v"(h23));
        }
        float sr = ar.x + ar.y, sz = az.x + az.y, sn = an.x + an.y;
        // quad reduce (DPP, VALU-only)
        sr += DPPF(sr, QP_XOR1); sr += DPPF(sr, QP_XOR2);
        sz += DPPF(sz, QP_XOR1); sz += DPPF(sz, QP_XOR2);
        sn += DPPF(sn, QP_XOR1); sn += DPPF(sn, QP_XOR2);
        // gi broadcast within quad (q0=r, q1=z, q2=n)
        const float gir = DPPF(gi_cur, QP_B0);
        const float giz = DPPF(gi_cur, QP_B1);
        const float gin = DPPF(gi_cur, QP_B2);
        const float hold = h_l[cur][hslot];
        const float r = 1.f / (1.f + __expf(-(gir + sr + bhr)));
        const float z = 1.f / (1.f + __expf(-(giz + sz + bhz)));
        const float nx = gin + r * (sn + bhn);
        const float n = 1.f - 2.f / (1.f + __expf(2.f * nx));   // tanh
        const float hn = n + z * (hold - n);
        if (q == 0) h_l[cur ^ 1][hslot] = hn;
        if (q == 3) {
            if (seq_out) seq_out[((size_t)(b * LQn + l)) * (2 * Hn) + dir * Hn + j] = hn;
            if (final_out && step == LQn - 1) final_out[b * 2 * Hn + dir * Hn + j] = hn;
        }
        cur ^= 1;
        __syncthreads();
    }
}

// =================== K5: classifier MLP ===================
__global__ __launch_bounds__(256) void k_cls(
    const float* __restrict__ cls_in,
    const float* __restrict__ c1w, const float* __restrict__ c1b,
    const float* __restrict__ c2w, const float* __restrict__ c2b,
    const float* __restrict__ c3w, const float* __restrict__ c3b,
    float* __restrict__ out)
{
    __shared__ float ci[256], y1[128], y2[64];
    const int b = blockIdx.x, tid = threadIdx.x;
    ci[tid] = cls_in[b * 256 + tid];
    __syncthreads();
    if (tid < 128) { float a = c1b[tid]; for (int i = 0; i < 256; ++i) a += ci[i] * c1w[i * 128 + tid]; y1[tid] = a; }
    __syncthreads();
    if (tid < 64)  { float a = c2b[tid]; for (int i = 0; i < 128; ++i) a += y1[i] * c2w[i * 64 + tid];  y2[tid] = a; }
    __syncthreads();
    if (tid < 6)   { float a = c3b[tid]; for (int i = 0; i < 64; ++i)  a += y2[i] * c3w[i * 6 + tid];   out[b * 6 + tid] = a; }
}

// =================== launch ===================
extern "C" void kernel_launch(void* const* d_in, const int* in_sizes, int n_in,
                              void* d_out, int out_size, void* d_ws, size_t ws_size,
                              hipStream_t stream)
{
    const float* x        = (const float*)d_in[0];
    const float* tsteps   = (const float*)d_in[1];
    const float* qtimes   = (const float*)d_in[2];
    const float* lin_w    = (const float*)d_in[3];
    const float* lin_b    = (const float*)d_in[4];
    const float* per_w    = (const float*)d_in[5];
    const float* per_b    = (const float*)d_in[6];
    const float* wq       = (const float*)d_in[7];
    const float* bq       = (const float*)d_in[8];
    const float* wk       = (const float*)d_in[9];
    const float* bk       = (const float*)d_in[10];
    const float* wo       = (const float*)d_in[11];
    const float* bo       = (const float*)d_in[12];
    const float* g0_wih   = (const float*)d_in[13];
    const float* g0_whh   = (const float*)d_in[14];
    const float* g0_bih   = (const float*)d_in[15];
    const float* g0_bhh   = (const float*)d_in[16];
    const float* g1_wih   = (const float*)d_in[17];
    const float* g1_whh   = (const float*)d_in[18];
    const float* g1_bih   = (const float*)d_in[19];
    const float* g1_bhh   = (const float*)d_in[20];
    const float* c1w      = (const float*)d_in[21];
    const float* c1b      = (const float*)d_in[22];
    const float* c2w      = (const float*)d_in[23];
    const float* c2b      = (const float*)d_in[24];
    const float* c3w      = (const float*)d_in[25];
    const float* c3b      = (const float*)d_in[26];
    float* out = (float*)d_out;
    float* ws  = (float*)d_ws;

    float* Cws   = ws + WS_C;
    float* attB  = ws + WS_ATT;
    float* Wt    = ws + WS_WT;
    float* bias2 = ws + WS_B2;
    float* clsin = ws + WS_CLS;
    float* g0buf = ws + WS_G0;
    float* gibuf = ws + WS_GI;

    k_coeff<<<128, 128, 0, stream>>>(qtimes, lin_w, lin_b, per_w, per_b, wq, bq, wk, bk, Cws);
    k_fuse<<<99, 256, 0, stream>>>(g0_wih, wo, bo, g0_bih, Wt, bias2);
    k_attn<<<256, 256, 0, stream>>>(x, tsteps, Cws, attB);

    // layer 0: gi = att @ Wt^T + bias2   (A: 8192x32, B: 768x32)
    k_gemm_nt<<<dim3(128, 12), 256, 0, stream>>>(attB, Wt, bias2, gibuf, 768, 32);
    k_gru<<<128, 512, 0, stream>>>(gibuf, g0_whh, g0_bhh, g0buf, nullptr);

    // layer 1: gi = g0 @ wih^T + bih     (A: 8192x256, B: 768x256)
    k_gemm_nt<<<dim3(128, 12), 256, 0, stream>>>(g0buf, g1_wih, g1_bih, gibuf, 768, 256);
    k_gru<<<128, 512, 0, stream>>>(gibuf, g1_whh, g1_bhh, nullptr, clsin);

    k_cls<<<64, 256, 0, stream>>>(clsin, c1w, c1b, c2w, c2b, c3w, c3b, out);
}

// Round 3
// 471.611 us; speedup vs baseline: 1.6396x; 1.3251x over previous
//
#include <hip/hip_runtime.h>
#include <math.h>

#define Bn   64
#define Ln   4096
#define LQn  128
#define Dn   32
#define ETn  128
#define Hn   128
#define G3n  384
#define NDEG 12

typedef __attribute__((ext_vector_type(2))) float f32x2;

// DPP helpers (VALU cross-lane, no LDS pipe)
#define DPPF(x, ctrl) __int_as_float(__builtin_amdgcn_update_dpp(0, __float_as_int(x), (ctrl), 0xF, 0xF, true))
#define QP_XOR1 0xB1   // quad_perm [1,0,3,2]
#define QP_XOR2 0x4E   // quad_perm [2,3,0,1]
#define QP_B0   0x00
#define QP_B1   0x55
#define QP_B2   0xAA
#define QP_B3   0xFF

// ---- workspace layout (float offsets) ----
#define WS_C    0                          // 128*12
#define WS_WT   4096                       // 768*32
#define WS_B2   (WS_WT + 768*32)           // 768 (pad 1024)
#define WS_CLS  (WS_B2 + 1024)             // 64*256
#define WS_G0   (WS_CLS + Bn*2*Hn)         // 8192*256  (accP/sP alias here pre-GRU0)
#define WS_GI   (WS_G0 + Bn*LQn*2*Hn)      // 8192*768
// aliases inside WS_G0 (dead once k_gemm_att consumed them):
#define WS_ACCP WS_G0                      // 4*8192*32 = 1048576
#define WS_SP   (WS_G0 + 1048576)          // 4*8192   = 32768

// =================== K1: per-query score-polynomial coefficients ===================
__global__ __launch_bounds__(128) void k_coeff(
    const float* __restrict__ qtimes, const float* __restrict__ lin_w,
    const float* __restrict__ lin_b, const float* __restrict__ per_w,
    const float* __restrict__ per_b, const float* __restrict__ wq,
    const float* __restrict__ bq, const float* __restrict__ wk,
    const float* __restrict__ bk, float* __restrict__ C)
{
    __shared__ float qe[ETn], qp[ETn], qt[ETn];
    const int q = blockIdx.x, tid = threadIdx.x;
    const float t = qtimes[q];
    const float lw = lin_w[0], lb = lin_b[0];
    qe[tid] = (tid == 0) ? (t * lw + lb) : sinf(t * per_w[tid - 1] + per_b[tid - 1]);
    __syncthreads();
    {
        float a = bq[tid];
        for (int i = 0; i < ETn; ++i) a += qe[i] * wq[i * ETn + tid];
        qp[tid] = a;
    }
    __syncthreads();
    {
        float a = 0.f;
        for (int e = 0; e < ETn; ++e) a += qp[e] * wk[tid * ETn + e];
        qt[tid] = a;
    }
    __syncthreads();
    if (tid < NDEG) {
        const int d = tid;
        float Cd = 0.f;
        for (int j = 0; j < ETn - 1; ++j) {
            float w = per_w[j], bb = per_b[j];
            float sb = sinf(bb), cb = cosf(bb);
            float sd = ((d & 3) == 0) ? sb : ((d & 3) == 1) ? cb : ((d & 3) == 2) ? -sb : -cb;
            float wp = 1.f;
            for (int u = 1; u <= d; ++u) wp *= w / (float)u;   // w^d / d!
            Cd += qt[j + 1] * wp * sd;
        }
        if (d == 0) {
            float qb = 0.f;
            for (int e = 0; e < ETn; ++e) qb += qp[e] * bk[e];
            Cd += qt[0] * lb + qb;
        }
        if (d == 1) Cd += qt[0] * lw;
        C[q * NDEG + d] = Cd * 0.08838834764831845f;   // 1/sqrt(128)
    }
}

// =================== K1b: fold wo (+bo) into layer-0 wih ===================
__global__ __launch_bounds__(256) void k_fuse(
    const float* __restrict__ wih, const float* __restrict__ wo,
    const float* __restrict__ bo, const float* __restrict__ bih,
    float* __restrict__ Wt, float* __restrict__ bias2)
{
    const int t = blockIdx.x * 256 + threadIdx.x;
    if (t < 768 * 32) {
        const int o = t >> 5, d = t & 31;
        const float* wr = wih + (size_t)o * 128;
        const float* wc = wo + (size_t)d * 128;
        float a = 0.f;
        for (int h = 0; h < 128; ++h) a += wr[h] * wc[h];
        Wt[t] = a;
    } else if (t < 768 * 33) {
        const int o = t - 768 * 32;
        const float* wr = wih + (size_t)o * 128;
        float a = bih[o];
        for (int h = 0; h < 128; ++h) a += bo[h] * wr[h];
        bias2[o] = a;
    }
}

// =================== K2: attention, unnormalized (no max-sub: |score| <= ~6) ===================
// grid 256 = (b, lsplit); 512 threads = (i = tid&3, qt = (tid>>2)&31, ls2 = tid>>7)
// lane: computes p for q_own = 4qt+i, DPP-quad broadcast; acc tile 4q x 8d; x direct from global.
#define ACC8(m, pv) \
    acc[m][0].x = fmaf(pv, xa.x, acc[m][0].x); acc[m][0].y = fmaf(pv, xa.y, acc[m][0].y); \
    acc[m][0].z = fmaf(pv, xa.z, acc[m][0].z); acc[m][0].w = fmaf(pv, xa.w, acc[m][0].w); \
    acc[m][1].x = fmaf(pv, xb.x, acc[m][1].x); acc[m][1].y = fmaf(pv, xb.y, acc[m][1].y); \
    acc[m][1].z = fmaf(pv, xb.z, acc[m][1].z); acc[m][1].w = fmaf(pv, xb.w, acc[m][1].w);

__global__ __launch_bounds__(512, 2) void k_attn(
    const float* __restrict__ x, const float* __restrict__ tsteps,
    const float* __restrict__ Cc, float* __restrict__ accP, float* __restrict__ sP)
{
    __shared__ float slab[4][128][36];
    const int tid = threadIdx.x;
    const int b = blockIdx.x >> 2, lsplit = blockIdx.x & 3;
    const int i = tid & 3, qt = (tid >> 2) & 31, ls2 = tid >> 7;
    const int qown = 4 * qt + i;

    float c[NDEG];
#pragma unroll
    for (int d = 0; d < NDEG; ++d) c[d] = Cc[qown * NDEG + d];

    const int l0 = lsplit * 1024 + ls2 * 256;
    const float4* tg4 = (const float4*)(tsteps + (size_t)b * Ln + l0);
    const float4* xg  = (const float4*)(x + ((size_t)b * Ln + l0) * Dn);

    float4 acc[4][2];
#pragma unroll
    for (int m = 0; m < 4; ++m)
#pragma unroll
        for (int e = 0; e < 2; ++e) { acc[m][e].x = 0.f; acc[m][e].y = 0.f; acc[m][e].z = 0.f; acc[m][e].w = 0.f; }
    float s_own = 0.f;

    for (int k = 0; k < 64; ++k) {
        const float4 t4 = tg4[k];
#pragma unroll
        for (int jj = 0; jj < 4; ++jj) {
            const float t = (jj == 0) ? t4.x : (jj == 1) ? t4.y : (jj == 2) ? t4.z : t4.w;
            float sc = c[NDEG - 1];
#pragma unroll
            for (int d = NDEG - 2; d >= 0; --d) sc = fmaf(sc, t, c[d]);
            const float pe = __expf(sc);
            s_own += pe;
            const float p0 = DPPF(pe, QP_B0);
            const float p1 = DPPF(pe, QP_B1);
            const float p2 = DPPF(pe, QP_B2);
            const float p3 = DPPF(pe, QP_B3);
            const int lrow = (k * 4 + jj) * 8;
            const float4 xa = xg[lrow + 2 * i];
            const float4 xb = xg[lrow + 2 * i + 1];
            ACC8(0, p0) ACC8(1, p1) ACC8(2, p2) ACC8(3, p3)
        }
    }
    // ---- in-block combine across ls2 ----
#pragma unroll
    for (int m = 0; m < 4; ++m) {
        *(float4*)&slab[ls2][4 * qt + m][8 * i]     = acc[m][0];
        *(float4*)&slab[ls2][4 * qt + m][8 * i + 4] = acc[m][1];
    }
    slab[ls2][qown][32] = s_own;
    __syncthreads();
    const int q = tid & 127, part = tid >> 7;
#pragma unroll
    for (int j = 0; j < 2; ++j) {
        const int off = (part * 2 + j) * 4;
        float4 r  = *(float4*)&slab[0][q][off];
        float4 r1 = *(float4*)&slab[1][q][off];
        float4 r2 = *(float4*)&slab[2][q][off];
        float4 r3 = *(float4*)&slab[3][q][off];
        r.x += r1.x + r2.x + r3.x; r.y += r1.y + r2.y + r3.y;
        r.z += r1.z + r2.z + r3.z; r.w += r1.w + r2.w + r3.w;
        *(float4*)&accP[((((size_t)lsplit * Bn + b) * LQn + q) * 32) + off] = r;
    }
    if (part == 0) {
        sP[((size_t)lsplit * Bn + b) * LQn + q] =
            slab[0][q][32] + slab[1][q][32] + slab[2][q][32] + slab[3][q][32];
    }
}

// =================== K3a: GEMM layer-0: A = (sum_ls accP)/(sum_ls sP), K=32 ===================
__global__ __launch_bounds__(256) void k_gemm_att(
    const float* __restrict__ accP, const float* __restrict__ sP,
    const float* __restrict__ Bm, const float* __restrict__ bias,
    float* __restrict__ Cm)
{
    __shared__ float4 A_l[64 * 8];
    __shared__ float4 B_l[64 * 8];
    const int tid = threadIdx.x;
    const int m0 = blockIdx.x * 64, n0 = blockIdx.y * 64;
    const int r0 = (tid >> 4) << 2, c0 = (tid & 15) << 2;
    float acc[4][4] = {};
    const float4* Ag = (const float4*)accP;
    const float4* Bg = (const float4*)Bm;

#pragma unroll
    for (int w = 0; w < 2; ++w) {
        const int idx = tid + w * 256;
        const int row = idx >> 3, c4 = idx & 7;
        const int sc = (c4 + row + (row >> 2)) & 7;
        const int m = m0 + row;
        float4 a0 = Ag[(size_t)m * 8 + c4];
        float4 a1 = Ag[((size_t)8192  + m) * 8 + c4];
        float4 a2 = Ag[((size_t)16384 + m) * 8 + c4];
        float4 a3 = Ag[((size_t)24576 + m) * 8 + c4];
        const float inv = 1.f / (sP[m] + sP[8192 + m] + sP[16384 + m] + sP[24576 + m]);
        float4 av;
        av.x = (a0.x + a1.x + a2.x + a3.x) * inv;
        av.y = (a0.y + a1.y + a2.y + a3.y) * inv;
        av.z = (a0.z + a1.z + a2.z + a3.z) * inv;
        av.w = (a0.w + a1.w + a2.w + a3.w) * inv;
        A_l[row * 8 + sc] = av;
        B_l[row * 8 + sc] = Bg[(size_t)(n0 + row) * 8 + c4];
    }
    __syncthreads();
#pragma unroll
    for (int k4 = 0; k4 < 8; ++k4) {
        float4 av[4], bv[4];
#pragma unroll
        for (int j = 0; j < 4; ++j) {
            const int ra = r0 + j;
            av[j] = A_l[ra * 8 + ((k4 + ra + (ra >> 2)) & 7)];
        }
#pragma unroll
        for (int j = 0; j < 4; ++j) {
            const int rb = c0 + j;
            bv[j] = B_l[rb * 8 + ((k4 + rb + (rb >> 2)) & 7)];
        }
#pragma unroll
        for (int ri = 0; ri < 4; ++ri)
#pragma unroll
            for (int ci = 0; ci < 4; ++ci)
                acc[ri][ci] += av[ri].x * bv[ci].x + av[ri].y * bv[ci].y
                             + av[ri].z * bv[ci].z + av[ri].w * bv[ci].w;
    }
#pragma unroll
    for (int ri = 0; ri < 4; ++ri) {
        float4 o4;
        o4.x = acc[ri][0] + bias[n0 + c0 + 0];
        o4.y = acc[ri][1] + bias[n0 + c0 + 1];
        o4.z = acc[ri][2] + bias[n0 + c0 + 2];
        o4.w = acc[ri][3] + bias[n0 + c0 + 3];
        *(float4*)&Cm[(size_t)(m0 + r0 + ri) * 768 + n0 + c0] = o4;
    }
}

// =================== K3b: tiled f32 GEMM  C = A(MxK) @ B(NxK)^T + bias ===================
__global__ __launch_bounds__(256) void k_gemm_nt(
    const float* __restrict__ A, const float* __restrict__ Bm,
    const float* __restrict__ bias, float* __restrict__ Cm,
    int N, int K)
{
    __shared__ float4 A_l[64 * 8];
    __shared__ float4 B_l[64 * 8];
    const int tid = threadIdx.x;
    const int m0 = blockIdx.x * 64, n0 = blockIdx.y * 64;
    const int r0 = (tid >> 4) << 2, c0 = (tid & 15) << 2;
    const int K4 = K >> 2;
    float acc[4][4] = {};
    const float4* Ag = (const float4*)A;
    const float4* Bg = (const float4*)Bm;

    for (int k0 = 0; k0 < K4; k0 += 8) {
        __syncthreads();
#pragma unroll
        for (int w = 0; w < 2; ++w) {
            const int idx = tid + w * 256;
            const int row = idx >> 3, c4 = idx & 7;
            const int sc = (c4 + row + (row >> 2)) & 7;
            A_l[row * 8 + sc] = Ag[(size_t)(m0 + row) * K4 + k0 + c4];
            B_l[row * 8 + sc] = Bg[(size_t)(n0 + row) * K4 + k0 + c4];
        }
        __syncthreads();
#pragma unroll
        for (int k4 = 0; k4 < 8; ++k4) {
            float4 av[4], bv[4];
#pragma unroll
            for (int j = 0; j < 4; ++j) {
                const int ra = r0 + j;
                av[j] = A_l[ra * 8 + ((k4 + ra + (ra >> 2)) & 7)];
            }
#pragma unroll
            for (int j = 0; j < 4; ++j) {
                const int rb = c0 + j;
                bv[j] = B_l[rb * 8 + ((k4 + rb + (rb >> 2)) & 7)];
            }
#pragma unroll
            for (int ri = 0; ri < 4; ++ri)
#pragma unroll
                for (int ci = 0; ci < 4; ++ci)
                    acc[ri][ci] += av[ri].x * bv[ci].x + av[ri].y * bv[ci].y
                                 + av[ri].z * bv[ci].z + av[ri].w * bv[ci].w;
        }
    }
#pragma unroll
    for (int ri = 0; ri < 4; ++ri) {
        float4 o4;
        o4.x = acc[ri][0] + bias[n0 + c0 + 0];
        o4.y = acc[ri][1] + bias[n0 + c0 + 1];
        o4.z = acc[ri][2] + bias[n0 + c0 + 2];
        o4.w = acc[ri][3] + bias[n0 + c0 + 3];
        *(float4*)&Cm[(size_t)(m0 + r0 + ri) * N + n0 + c0] = o4;
    }
}

// =================== K4: GRU recurrence — quad-per-unit, DPP combine, 1 barrier/step ===================
__global__ __launch_bounds__(512, 2) void k_gru(
    const float* __restrict__ gi, const float* __restrict__ whh,
    const float* __restrict__ bhh, float* __restrict__ seq_out,
    float* __restrict__ final_out)
{
    __shared__ float h_l[2][4 * 36];
    const int tid = threadIdx.x;
    const int b = blockIdx.x >> 1, dir = blockIdx.x & 1;
    const int j = tid >> 2, q = tid & 3;

    f32x2 wr[16], wz[16], wn[16];
    {
        const float* wb = whh + ((size_t)dir * G3n + j) * Hn + 32 * q;
        const f32x2* p0 = (const f32x2*)(wb);
        const f32x2* p1 = (const f32x2*)(wb + (size_t)128 * Hn);
        const f32x2* p2 = (const f32x2*)(wb + (size_t)256 * Hn);
#pragma unroll
        for (int k = 0; k < 16; ++k) { wr[k] = p0[k]; wz[k] = p1[k]; wn[k] = p2[k]; }
    }
    const float bhr = bhh[dir * G3n + j];
    const float bhz = bhh[dir * G3n + 128 + j];
    const float bhn = bhh[dir * G3n + 256 + j];

    if (tid < 144) h_l[0][tid] = 0.f;
    __syncthreads();

    const float* gib = gi + (size_t)b * LQn * 768 + dir * G3n;
    const int hslot = (j >> 5) * 36 + (j & 31);

    float gi_nxt = (q < 3) ? gib[(size_t)(dir ? LQn - 1 : 0) * 768 + q * Hn + j] : 0.f;

    int cur = 0;
    for (int step = 0; step < LQn; ++step) {
        const int l = dir ? (LQn - 1 - step) : step;
        const float gi_cur = gi_nxt;
        if (step + 1 < LQn && q < 3) {
            const int ln = dir ? (LQn - 2 - step) : (step + 1);
            gi_nxt = gib[(size_t)ln * 768 + q * Hn + j];
        }
        const float4* hq = (const float4*)(&h_l[cur][q * 36]);
        f32x2 ar = {0.f, 0.f}, az = {0.f, 0.f}, an = {0.f, 0.f};
#pragma unroll
        for (int cc = 0; cc < 8; ++cc) {
            float4 hv = hq[cc];
            f32x2 h01; h01.x = hv.x; h01.y = hv.y;
            f32x2 h23; h23.x = hv.z; h23.y = hv.w;
            asm("v_pk_fma_f32 %0, %1, %2, %0" : "+v"(ar) : "v"(wr[2 * cc]),     "v"(h01));
            asm("v_pk_fma_f32 %0, %1, %2, %0" : "+v"(az) : "v"(wz[2 * cc]),     "v"(h01));
            asm("v_pk_fma_f32 %0, %1, %2, %0" : "+v"(an) : "v"(wn[2 * cc]),     "v"(h01));
            asm("v_pk_fma_f32 %0, %1, %2, %0" : "+v"(ar) : "v"(wr[2 * cc + 1]), "v"(h23));
            asm("v_pk_fma_f32 %0, %1, %2, %0" : "+v"(az) : "v"(wz[2 * cc + 1]), "v"(h23));
            asm("v_pk_fma_f32 %0, %1, %2, %0" : "+v"(an) : "v"(wn[2 * cc + 1]), "v"(h23));
        }
        float sr = ar.x + ar.y, sz = az.x + az.y, sn = an.x + an.y;
        sr += DPPF(sr, QP_XOR1); sr += DPPF(sr, QP_XOR2);
        sz += DPPF(sz, QP_XOR1); sz += DPPF(sz, QP_XOR2);
        sn += DPPF(sn, QP_XOR1); sn += DPPF(sn, QP_XOR2);
        const float gir = DPPF(gi_cur, QP_B0);
        const float giz = DPPF(gi_cur, QP_B1);
        const float gin = DPPF(gi_cur, QP_B2);
        const float hold = h_l[cur][hslot];
        const float r = 1.f / (1.f + __expf(-(gir + sr + bhr)));
        const float z = 1.f / (1.f + __expf(-(giz + sz + bhz)));
        const float nx = gin + r * (sn + bhn);
        const float n = 1.f - 2.f / (1.f + __expf(2.f * nx));   // tanh
        const float hn = n + z * (hold - n);
        if (q == 0) h_l[cur ^ 1][hslot] = hn;
        if (q == 3) {
            if (seq_out) seq_out[((size_t)(b * LQn + l)) * (2 * Hn) + dir * Hn + j] = hn;
            if (final_out && step == LQn - 1) final_out[b * 2 * Hn + dir * Hn + j] = hn;
        }
        cur ^= 1;
        __syncthreads();
    }
}

// =================== K5: classifier MLP ===================
__global__ __launch_bounds__(256) void k_cls(
    const float* __restrict__ cls_in,
    const float* __restrict__ c1w, const float* __restrict__ c1b,
    const float* __restrict__ c2w, const float* __restrict__ c2b,
    const float* __restrict__ c3w, const float* __restrict__ c3b,
    float* __restrict__ out)
{
    __shared__ float ci[256], y1[128], y2[64];
    const int b = blockIdx.x, tid = threadIdx.x;
    ci[tid] = cls_in[b * 256 + tid];
    __syncthreads();
    if (tid < 128) { float a = c1b[tid]; for (int i = 0; i < 256; ++i) a += ci[i] * c1w[i * 128 + tid]; y1[tid] = a; }
    __syncthreads();
    if (tid < 64)  { float a = c2b[tid]; for (int i = 0; i < 128; ++i) a += y1[i] * c2w[i * 64 + tid];  y2[tid] = a; }
    __syncthreads();
    if (tid < 6)   { float a = c3b[tid]; for (int i = 0; i < 64; ++i)  a += y2[i] * c3w[i * 6 + tid];   out[b * 6 + tid] = a; }
}

// =================== launch ===================
extern "C" void kernel_launch(void* const* d_in, const int* in_sizes, int n_in,
                              void* d_out, int out_size, void* d_ws, size_t ws_size,
                              hipStream_t stream)
{
    const float* x        = (const float*)d_in[0];
    const float* tsteps   = (const float*)d_in[1];
    const float* qtimes   = (const float*)d_in[2];
    const float* lin_w    = (const float*)d_in[3];
    const float* lin_b    = (const float*)d_in[4];
    const float* per_w    = (const float*)d_in[5];
    const float* per_b    = (const float*)d_in[6];
    const float* wq       = (const float*)d_in[7];
    const float* bq       = (const float*)d_in[8];
    const float* wk       = (const float*)d_in[9];
    const float* bk       = (const float*)d_in[10];
    const float* wo       = (const float*)d_in[11];
    const float* bo       = (const float*)d_in[12];
    const float* g0_wih   = (const float*)d_in[13];
    const float* g0_whh   = (const float*)d_in[14];
    const float* g0_bih   = (const float*)d_in[15];
    const float* g0_bhh   = (const float*)d_in[16];
    const float* g1_wih   = (const float*)d_in[17];
    const float* g1_whh   = (const float*)d_in[18];
    const float* g1_bih   = (const float*)d_in[19];
    const float* g1_bhh   = (const float*)d_in[20];
    const float* c1w      = (const float*)d_in[21];
    const float* c1b      = (const float*)d_in[22];
    const float* c2w      = (const float*)d_in[23];
    const float* c2b      = (const float*)d_in[24];
    const float* c3w      = (const float*)d_in[25];
    const float* c3b      = (const float*)d_in[26];
    float* out = (float*)d_out;
    float* ws  = (float*)d_ws;

    float* Cws   = ws + WS_C;
    float* Wt    = ws + WS_WT;
    float* bias2 = ws + WS_B2;
    float* clsin = ws + WS_CLS;
    float* g0buf = ws + WS_G0;
    float* accP  = ws + WS_ACCP;
    float* sPb   = ws + WS_SP;
    float* gibuf = ws + WS_GI;

    k_coeff<<<128, 128, 0, stream>>>(qtimes, lin_w, lin_b, per_w, per_b, wq, bq, wk, bk, Cws);
    k_fuse<<<99, 256, 0, stream>>>(g0_wih, wo, bo, g0_bih, Wt, bias2);
    k_attn<<<256, 512, 0, stream>>>(x, tsteps, Cws, accP, sPb);

    // layer 0: gi = att @ Wt^T + bias2 (att assembled in-GEMM from accP/sP)
    k_gemm_att<<<dim3(128, 12), 256, 0, stream>>>(accP, sPb, Wt, bias2, gibuf);
    k_gru<<<128, 512, 0, stream>>>(gibuf, g0_whh, g0_bhh, g0buf, nullptr);

    // layer 1: gi = g0 @ wih^T + bih   (A: 8192x256, B: 768x256)
    k_gemm_nt<<<dim3(128, 12), 256, 0, stream>>>(g0buf, g1_wih, g1_bih, gibuf, 768, 256);
    k_gru<<<128, 512, 0, stream>>>(gibuf, g1_whh, g1_bhh, nullptr, clsin);

    k_cls<<<64, 256, 0, stream>>>(clsin, c1w, c1b, c2w, c2b, c3w, c3b, out);
}

// Round 4
// 362.149 us; speedup vs baseline: 2.1351x; 1.3023x over previous
//
#include <hip/hip_runtime.h>
#include <math.h>

#define Bn   64
#define Ln   4096
#define LQn  128
#define Dn   32
#define ETn  128
#define Hn   128
#define G3n  384
#define NDEG 12

typedef __attribute__((ext_vector_type(2))) float f32x2;

// DPP helpers (VALU cross-lane, no LDS pipe)
#define DPPF(x, ctrl) __int_as_float(__builtin_amdgcn_update_dpp(0, __float_as_int(x), (ctrl), 0xF, 0xF, true))
#define QP_XOR1 0xB1   // quad_perm [1,0,3,2]
#define QP_XOR2 0x4E   // quad_perm [2,3,0,1]
#define QP_B0   0x00
#define QP_B1   0x55
#define QP_B2   0xAA
#define QP_B3   0xFF

// odd sin polynomial, |x| <= ~0.5, err < 5e-9
__device__ __forceinline__ float sin_poly(float x) {
    const float x2 = x * x;
    float r = -1.9841270114e-04f;               // -1/5040
    r = fmaf(r, x2,  8.3333337680e-03f);        //  1/120
    r = fmaf(r, x2, -1.6666667163e-01f);        // -1/6
    return fmaf(r * x2, x, x);
}
// even cos polynomial, |x| <= ~0.5, err < 3e-10
__device__ __forceinline__ float cos_poly(float x) {
    const float x2 = x * x;
    float r =  2.4801587642e-05f;               //  1/40320 approx tail start
    r = fmaf(r, x2, -1.3888888899e-03f);        // -1/720
    r = fmaf(r, x2,  4.1666667908e-02f);        //  1/24
    r = fmaf(r, x2, -5.0000000000e-01f);        // -1/2
    return fmaf(r, x2, 1.0f);
}

// ---- workspace layout (float offsets) ----
#define WS_C    0                          // 128*12
#define WS_WT   4096                       // 768*32
#define WS_B2   (WS_WT + 768*32)           // 768 (pad 1024)
#define WS_CLS  (WS_B2 + 1024)             // 64*256
#define WS_G0   (WS_CLS + Bn*2*Hn)         // 8192*256  (transient aliases below)
#define WS_GI   (WS_G0 + Bn*LQn*2*Hn)      // 8192*768
// transient aliases inside WS_G0 (dead before the region's next use):
#define WS_QPB  WS_G0                      // 128*128 qp matrix (k_qp -> k_qtc)
#define WS_BAS  (WS_G0 + 16384)            // 12*128 basis     (k_basis -> k_qtc)
#define WS_ACCP WS_G0                      // 4*8192*32 (k_attn -> k_gemm_att)
#define WS_SP   (WS_G0 + 1048576)          // 4*8192

// =================== K1a: basis[d][j] = pw_j^d/d! * phase(pb_j, d) ===================
__global__ __launch_bounds__(128) void k_basis(
    const float* __restrict__ per_w, const float* __restrict__ per_b,
    float* __restrict__ basis)
{
    const int j = threadIdx.x;
    if (j >= ETn - 1) return;
    const float w = per_w[j], b = per_b[j];
    const float sb = sin_poly(b), cb = cos_poly(b);
    float wp = 1.f;
#pragma unroll
    for (int d = 0; d < NDEG; ++d) {
        const float sd = ((d & 3) == 0) ? sb : ((d & 3) == 1) ? cb : ((d & 3) == 2) ? -sb : -cb;
        basis[d * 128 + j] = wp * sd;
        wp *= w / (float)(d + 1);
    }
}

// =================== K1b: qp[q][e] = sum_i qe[q][i]*wq[i][e] + bq[e] ===================
__global__ __launch_bounds__(128) void k_qp(
    const float* __restrict__ qtimes, const float* __restrict__ lin_w,
    const float* __restrict__ lin_b, const float* __restrict__ per_w,
    const float* __restrict__ per_b, const float* __restrict__ wq,
    const float* __restrict__ bq, float* __restrict__ qp)
{
    __shared__ float qe[ETn];
    const int q = blockIdx.x, e = threadIdx.x;
    const float t = qtimes[q];
    qe[e] = (e == 0) ? fmaf(t, lin_w[0], lin_b[0])
                     : sin_poly(fmaf(t, per_w[e - 1], per_b[e - 1]));
    __syncthreads();
    float a = bq[e];
#pragma unroll 16
    for (int i = 0; i < ETn; ++i) a = fmaf(qe[i], wq[i * ETn + e], a);
    qp[q * ETn + e] = a;
}

// =================== K1c: qt + coefficients C[q][d] ===================
__global__ __launch_bounds__(128) void k_qtc(
    const float* __restrict__ qp, const float* __restrict__ wk,
    const float* __restrict__ bk, const float* __restrict__ lin_w,
    const float* __restrict__ lin_b, const float* __restrict__ basis,
    float* __restrict__ C)
{
    __shared__ float qp_l[ETn], qt_l[ETn], red[96], qbk_red[32];
    const int q = blockIdx.x, tid = threadIdx.x;
    qp_l[tid] = qp[q * ETn + tid];
    __syncthreads();
    // qt[c] = sum_e qp[e]*wk[c][e]  (per-thread contiguous float4 row)
    {
        const float4* wk4 = (const float4*)(wk + (size_t)tid * ETn);
        const float4* qp4 = (const float4*)qp_l;
        float a = 0.f;
#pragma unroll
        for (int k = 0; k < 32; ++k) {
            const float4 w4 = wk4[k], p4 = qp4[k];
            a += w4.x * p4.x + w4.y * p4.y + w4.z * p4.z + w4.w * p4.w;
        }
        qt_l[tid] = a;
    }
    __syncthreads();
    if (tid < 96) {             // d = tid>>3 (12), g = tid&7 (8-way split of j)
        const int d = tid >> 3, g = tid & 7;
        float p = 0.f;
        for (int j = g; j < ETn - 1; j += 8) p = fmaf(qt_l[j + 1], basis[d * 128 + j], p);
        red[tid] = p;
    } else {                    // lanes 96..127: qbk partials
        const int g2 = tid - 96;
        float p = 0.f;
#pragma unroll
        for (int k = 0; k < 4; ++k) p = fmaf(qp_l[g2 + 32 * k], bk[g2 + 32 * k], p);
        qbk_red[g2] = p;
    }
    __syncthreads();
    if (tid < NDEG) {
        const int d = tid;
        float s = red[d * 8 + 0] + red[d * 8 + 1] + red[d * 8 + 2] + red[d * 8 + 3]
                + red[d * 8 + 4] + red[d * 8 + 5] + red[d * 8 + 6] + red[d * 8 + 7];
        if (d == 0) {
            float qbk = 0.f;
#pragma unroll
            for (int k = 0; k < 32; ++k) qbk += qbk_red[k];
            s += qt_l[0] * lin_b[0] + qbk;
        }
        if (d == 1) s += qt_l[0] * lin_w[0];
        C[q * NDEG + d] = s * 0.08838834764831845f;   // 1/sqrt(128)
    }
}

// =================== K1d: fold wo (+bo) into layer-0 wih ===================
__global__ __launch_bounds__(256) void k_fuse(
    const float* __restrict__ wih, const float* __restrict__ wo,
    const float* __restrict__ bo, const float* __restrict__ bih,
    float* __restrict__ Wt, float* __restrict__ bias2)
{
    const int t = blockIdx.x * 256 + threadIdx.x;
    if (t < 768 * 32) {
        const int o = t >> 5, d = t & 31;
        const float* wr = wih + (size_t)o * 128;
        const float* wc = wo + (size_t)d * 128;
        float a = 0.f;
        for (int h = 0; h < 128; ++h) a += wr[h] * wc[h];
        Wt[t] = a;
    } else if (t < 768 * 33) {
        const int o = t - 768 * 32;
        const float* wr = wih + (size_t)o * 128;
        float a = bih[o];
        for (int h = 0; h < 128; ++h) a += bo[h] * wr[h];
        bias2[o] = a;
    }
}

// =================== K2: attention, unnormalized (no max-sub: |score| <= ~6) ===================
#define ACC8(m, pv) \
    acc[m][0].x = fmaf(pv, xa.x, acc[m][0].x); acc[m][0].y = fmaf(pv, xa.y, acc[m][0].y); \
    acc[m][0].z = fmaf(pv, xa.z, acc[m][0].z); acc[m][0].w = fmaf(pv, xa.w, acc[m][0].w); \
    acc[m][1].x = fmaf(pv, xb.x, acc[m][1].x); acc[m][1].y = fmaf(pv, xb.y, acc[m][1].y); \
    acc[m][1].z = fmaf(pv, xb.z, acc[m][1].z); acc[m][1].w = fmaf(pv, xb.w, acc[m][1].w);

__global__ __launch_bounds__(512, 2) void k_attn(
    const float* __restrict__ x, const float* __restrict__ tsteps,
    const float* __restrict__ Cc, float* __restrict__ accP, float* __restrict__ sP)
{
    __shared__ float slab[4][128][36];
    const int tid = threadIdx.x;
    const int b = blockIdx.x >> 2, lsplit = blockIdx.x & 3;
    const int i = tid & 3, qt = (tid >> 2) & 31, ls2 = tid >> 7;
    const int qown = 4 * qt + i;

    float c[NDEG];
#pragma unroll
    for (int d = 0; d < NDEG; ++d) c[d] = Cc[qown * NDEG + d];

    const int l0 = lsplit * 1024 + ls2 * 256;
    const float4* tg4 = (const float4*)(tsteps + (size_t)b * Ln + l0);
    const float4* xg  = (const float4*)(x + ((size_t)b * Ln + l0) * Dn);

    float4 acc[4][2];
#pragma unroll
    for (int m = 0; m < 4; ++m)
#pragma unroll
        for (int e = 0; e < 2; ++e) { acc[m][e].x = 0.f; acc[m][e].y = 0.f; acc[m][e].z = 0.f; acc[m][e].w = 0.f; }
    float s_own = 0.f;

    for (int k = 0; k < 64; ++k) {
        const float4 t4 = tg4[k];
#pragma unroll
        for (int jj = 0; jj < 4; ++jj) {
            const float t = (jj == 0) ? t4.x : (jj == 1) ? t4.y : (jj == 2) ? t4.z : t4.w;
            float sc = c[NDEG - 1];
#pragma unroll
            for (int d = NDEG - 2; d >= 0; --d) sc = fmaf(sc, t, c[d]);
            const float pe = __expf(sc);
            s_own += pe;
            const float p0 = DPPF(pe, QP_B0);
            const float p1 = DPPF(pe, QP_B1);
            const float p2 = DPPF(pe, QP_B2);
            const float p3 = DPPF(pe, QP_B3);
            const int lrow = (k * 4 + jj) * 8;
            const float4 xa = xg[lrow + 2 * i];
            const float4 xb = xg[lrow + 2 * i + 1];
            ACC8(0, p0) ACC8(1, p1) ACC8(2, p2) ACC8(3, p3)
        }
    }
#pragma unroll
    for (int m = 0; m < 4; ++m) {
        *(float4*)&slab[ls2][4 * qt + m][8 * i]     = acc[m][0];
        *(float4*)&slab[ls2][4 * qt + m][8 * i + 4] = acc[m][1];
    }
    slab[ls2][qown][32] = s_own;
    __syncthreads();
    const int q = tid & 127, part = tid >> 7;
#pragma unroll
    for (int j = 0; j < 2; ++j) {
        const int off = (part * 2 + j) * 4;
        float4 r  = *(float4*)&slab[0][q][off];
        float4 r1 = *(float4*)&slab[1][q][off];
        float4 r2 = *(float4*)&slab[2][q][off];
        float4 r3 = *(float4*)&slab[3][q][off];
        r.x += r1.x + r2.x + r3.x; r.y += r1.y + r2.y + r3.y;
        r.z += r1.z + r2.z + r3.z; r.w += r1.w + r2.w + r3.w;
        *(float4*)&accP[((((size_t)lsplit * Bn + b) * LQn + q) * 32) + off] = r;
    }
    if (part == 0) {
        sP[((size_t)lsplit * Bn + b) * LQn + q] =
            slab[0][q][32] + slab[1][q][32] + slab[2][q][32] + slab[3][q][32];
    }
}

// =================== K3a: GEMM layer-0: A = (sum_ls accP)/(sum_ls sP), K=32 ===================
__global__ __launch_bounds__(256) void k_gemm_att(
    const float* __restrict__ accP, const float* __restrict__ sP,
    const float* __restrict__ Bm, const float* __restrict__ bias,
    float* __restrict__ Cm)
{
    __shared__ float4 A_l[64 * 8];
    __shared__ float4 B_l[64 * 8];
    const int tid = threadIdx.x;
    const int m0 = blockIdx.x * 64, n0 = blockIdx.y * 64;
    const int r0 = (tid >> 4) << 2, c0 = (tid & 15) << 2;
    float acc[4][4] = {};
    const float4* Ag = (const float4*)accP;
    const float4* Bg = (const float4*)Bm;

#pragma unroll
    for (int w = 0; w < 2; ++w) {
        const int idx = tid + w * 256;
        const int row = idx >> 3, c4 = idx & 7;
        const int sc = (c4 + row + (row >> 2)) & 7;
        const int m = m0 + row;
        float4 a0 = Ag[(size_t)m * 8 + c4];
        float4 a1 = Ag[((size_t)8192  + m) * 8 + c4];
        float4 a2 = Ag[((size_t)16384 + m) * 8 + c4];
        float4 a3 = Ag[((size_t)24576 + m) * 8 + c4];
        const float inv = 1.f / (sP[m] + sP[8192 + m] + sP[16384 + m] + sP[24576 + m]);
        float4 av;
        av.x = (a0.x + a1.x + a2.x + a3.x) * inv;
        av.y = (a0.y + a1.y + a2.y + a3.y) * inv;
        av.z = (a0.z + a1.z + a2.z + a3.z) * inv;
        av.w = (a0.w + a1.w + a2.w + a3.w) * inv;
        A_l[row * 8 + sc] = av;
        B_l[row * 8 + sc] = Bg[(size_t)(n0 + row) * 8 + c4];
    }
    __syncthreads();
#pragma unroll
    for (int k4 = 0; k4 < 8; ++k4) {
        float4 av[4], bv[4];
#pragma unroll
        for (int j = 0; j < 4; ++j) {
            const int ra = r0 + j;
            av[j] = A_l[ra * 8 + ((k4 + ra + (ra >> 2)) & 7)];
        }
#pragma unroll
        for (int j = 0; j < 4; ++j) {
            const int rb = c0 + j;
            bv[j] = B_l[rb * 8 + ((k4 + rb + (rb >> 2)) & 7)];
        }
#pragma unroll
        for (int ri = 0; ri < 4; ++ri)
#pragma unroll
            for (int ci = 0; ci < 4; ++ci)
                acc[ri][ci] += av[ri].x * bv[ci].x + av[ri].y * bv[ci].y
                             + av[ri].z * bv[ci].z + av[ri].w * bv[ci].w;
    }
#pragma unroll
    for (int ri = 0; ri < 4; ++ri) {
        float4 o4;
        o4.x = acc[ri][0] + bias[n0 + c0 + 0];
        o4.y = acc[ri][1] + bias[n0 + c0 + 1];
        o4.z = acc[ri][2] + bias[n0 + c0 + 2];
        o4.w = acc[ri][3] + bias[n0 + c0 + 3];
        *(float4*)&Cm[(size_t)(m0 + r0 + ri) * 768 + n0 + c0] = o4;
    }
}

// =================== K3b: tiled f32 GEMM  C = A(MxK) @ B(NxK)^T + bias ===================
__global__ __launch_bounds__(256) void k_gemm_nt(
    const float* __restrict__ A, const float* __restrict__ Bm,
    const float* __restrict__ bias, float* __restrict__ Cm,
    int N, int K)
{
    __shared__ float4 A_l[64 * 8];
    __shared__ float4 B_l[64 * 8];
    const int tid = threadIdx.x;
    const int m0 = blockIdx.x * 64, n0 = blockIdx.y * 64;
    const int r0 = (tid >> 4) << 2, c0 = (tid & 15) << 2;
    const int K4 = K >> 2;
    float acc[4][4] = {};
    const float4* Ag = (const float4*)A;
    const float4* Bg = (const float4*)Bm;

    for (int k0 = 0; k0 < K4; k0 += 8) {
        __syncthreads();
#pragma unroll
        for (int w = 0; w < 2; ++w) {
            const int idx = tid + w * 256;
            const int row = idx >> 3, c4 = idx & 7;
            const int sc = (c4 + row + (row >> 2)) & 7;
            A_l[row * 8 + sc] = Ag[(size_t)(m0 + row) * K4 + k0 + c4];
            B_l[row * 8 + sc] = Bg[(size_t)(n0 + row) * K4 + k0 + c4];
        }
        __syncthreads();
#pragma unroll
        for (int k4 = 0; k4 < 8; ++k4) {
            float4 av[4], bv[4];
#pragma unroll
            for (int j = 0; j < 4; ++j) {
                const int ra = r0 + j;
                av[j] = A_l[ra * 8 + ((k4 + ra + (ra >> 2)) & 7)];
            }
#pragma unroll
            for (int j = 0; j < 4; ++j) {
                const int rb = c0 + j;
                bv[j] = B_l[rb * 8 + ((k4 + rb + (rb >> 2)) & 7)];
            }
#pragma unroll
            for (int ri = 0; ri < 4; ++ri)
#pragma unroll
                for (int ci = 0; ci < 4; ++ci)
                    acc[ri][ci] += av[ri].x * bv[ci].x + av[ri].y * bv[ci].y
                                 + av[ri].z * bv[ci].z + av[ri].w * bv[ci].w;
        }
    }
#pragma unroll
    for (int ri = 0; ri < 4; ++ri) {
        float4 o4;
        o4.x = acc[ri][0] + bias[n0 + c0 + 0];
        o4.y = acc[ri][1] + bias[n0 + c0 + 1];
        o4.z = acc[ri][2] + bias[n0 + c0 + 2];
        o4.w = acc[ri][3] + bias[n0 + c0 + 3];
        *(float4*)&Cm[(size_t)(m0 + r0 + ri) * N + n0 + c0] = o4;
    }
}

// =================== K4: GRU recurrence — quad-per-unit, DPP combine, 1 barrier/step ===================
__global__ __launch_bounds__(512, 2) void k_gru(
    const float* __restrict__ gi, const float* __restrict__ whh,
    const float* __restrict__ bhh, float* __restrict__ seq_out,
    float* __restrict__ final_out)
{
    __shared__ float h_l[2][4 * 36];
    const int tid = threadIdx.x;
    const int b = blockIdx.x >> 1, dir = blockIdx.x & 1;
    const int j = tid >> 2, q = tid & 3;

    f32x2 wr[16], wz[16], wn[16];
    {
        const float* wb = whh + ((size_t)dir * G3n + j) * Hn + 32 * q;
        const f32x2* p0 = (const f32x2*)(wb);
        const f32x2* p1 = (const f32x2*)(wb + (size_t)128 * Hn);
        const f32x2* p2 = (const f32x2*)(wb + (size_t)256 * Hn);
#pragma unroll
        for (int k = 0; k < 16; ++k) { wr[k] = p0[k]; wz[k] = p1[k]; wn[k] = p2[k]; }
    }
    const float bhr = bhh[dir * G3n + j];
    const float bhz = bhh[dir * G3n + 128 + j];
    const float bhn = bhh[dir * G3n + 256 + j];

    if (tid < 144) h_l[0][tid] = 0.f;
    __syncthreads();

    const float* gib = gi + (size_t)b * LQn * 768 + dir * G3n;
    const int hslot = (j >> 5) * 36 + (j & 31);

    float gi_nxt = (q < 3) ? gib[(size_t)(dir ? LQn - 1 : 0) * 768 + q * Hn + j] : 0.f;

    int cur = 0;
    for (int step = 0; step < LQn; ++step) {
        const int l = dir ? (LQn - 1 - step) : step;
        const float gi_cur = gi_nxt;
        if (step + 1 < LQn && q < 3) {
            const int ln = dir ? (LQn - 2 - step) : (step + 1);
            gi_nxt = gib[(size_t)ln * 768 + q * Hn + j];
        }
        const float4* hq = (const float4*)(&h_l[cur][q * 36]);
        f32x2 ar = {0.f, 0.f}, az = {0.f, 0.f}, an = {0.f, 0.f};
#pragma unroll
        for (int cc = 0; cc < 8; ++cc) {
            float4 hv = hq[cc];
            f32x2 h01; h01.x = hv.x; h01.y = hv.y;
            f32x2 h23; h23.x = hv.z; h23.y = hv.w;
            asm("v_pk_fma_f32 %0, %1, %2, %0" : "+v"(ar) : "v"(wr[2 * cc]),     "v"(h01));
            asm("v_pk_fma_f32 %0, %1, %2, %0" : "+v"(az) : "v"(wz[2 * cc]),     "v"(h01));
            asm("v_pk_fma_f32 %0, %1, %2, %0" : "+v"(an) : "v"(wn[2 * cc]),     "v"(h01));
            asm("v_pk_fma_f32 %0, %1, %2, %0" : "+v"(ar) : "v"(wr[2 * cc + 1]), "v"(h23));
            asm("v_pk_fma_f32 %0, %1, %2, %0" : "+v"(az) : "v"(wz[2 * cc + 1]), "v"(h23));
            asm("v_pk_fma_f32 %0, %1, %2, %0" : "+v"(an) : "v"(wn[2 * cc + 1]), "v"(h23));
        }
        float sr = ar.x + ar.y, sz = az.x + az.y, sn = an.x + an.y;
        sr += DPPF(sr, QP_XOR1); sr += DPPF(sr, QP_XOR2);
        sz += DPPF(sz, QP_XOR1); sz += DPPF(sz, QP_XOR2);
        sn += DPPF(sn, QP_XOR1); sn += DPPF(sn, QP_XOR2);
        const float gir = DPPF(gi_cur, QP_B0);
        const float giz = DPPF(gi_cur, QP_B1);
        const float gin = DPPF(gi_cur, QP_B2);
        const float hold = h_l[cur][hslot];
        const float r = 1.f / (1.f + __expf(-(gir + sr + bhr)));
        const float z = 1.f / (1.f + __expf(-(giz + sz + bhz)));
        const float nx = gin + r * (sn + bhn);
        const float n = 1.f - 2.f / (1.f + __expf(2.f * nx));   // tanh
        const float hn = n + z * (hold - n);
        if (q == 0) h_l[cur ^ 1][hslot] = hn;
        if (q == 3) {
            if (seq_out) seq_out[((size_t)(b * LQn + l)) * (2 * Hn) + dir * Hn + j] = hn;
            if (final_out && step == LQn - 1) final_out[b * 2 * Hn + dir * Hn + j] = hn;
        }
        cur ^= 1;
        __syncthreads();
    }
}

// =================== K5: classifier MLP ===================
__global__ __launch_bounds__(256) void k_cls(
    const float* __restrict__ cls_in,
    const float* __restrict__ c1w, const float* __restrict__ c1b,
    const float* __restrict__ c2w, const float* __restrict__ c2b,
    const float* __restrict__ c3w, const float* __restrict__ c3b,
    float* __restrict__ out)
{
    __shared__ float ci[256], y1[128], y2[64];
    const int b = blockIdx.x, tid = threadIdx.x;
    ci[tid] = cls_in[b * 256 + tid];
    __syncthreads();
    if (tid < 128) { float a = c1b[tid]; for (int i = 0; i < 256; ++i) a += ci[i] * c1w[i * 128 + tid]; y1[tid] = a; }
    __syncthreads();
    if (tid < 64)  { float a = c2b[tid]; for (int i = 0; i < 128; ++i) a += y1[i] * c2w[i * 64 + tid];  y2[tid] = a; }
    __syncthreads();
    if (tid < 6)   { float a = c3b[tid]; for (int i = 0; i < 64; ++i)  a += y2[i] * c3w[i * 6 + tid];   out[b * 6 + tid] = a; }
}

// =================== launch ===================
extern "C" void kernel_launch(void* const* d_in, const int* in_sizes, int n_in,
                              void* d_out, int out_size, void* d_ws, size_t ws_size,
                              hipStream_t stream)
{
    const float* x        = (const float*)d_in[0];
    const float* tsteps   = (const float*)d_in[1];
    const float* qtimes   = (const float*)d_in[2];
    const float* lin_w    = (const float*)d_in[3];
    const float* lin_b    = (const float*)d_in[4];
    const float* per_w    = (const float*)d_in[5];
    const float* per_b    = (const float*)d_in[6];
    const float* wq       = (const float*)d_in[7];
    const float* bq       = (const float*)d_in[8];
    const float* wk       = (const float*)d_in[9];
    const float* bk       = (const float*)d_in[10];
    const float* wo       = (const float*)d_in[11];
    const float* bo       = (const float*)d_in[12];
    const float* g0_wih   = (const float*)d_in[13];
    const float* g0_whh   = (const float*)d_in[14];
    const float* g0_bih   = (const float*)d_in[15];
    const float* g0_bhh   = (const float*)d_in[16];
    const float* g1_wih   = (const float*)d_in[17];
    const float* g1_whh   = (const float*)d_in[18];
    const float* g1_bih   = (const float*)d_in[19];
    const float* g1_bhh   = (const float*)d_in[20];
    const float* c1w      = (const float*)d_in[21];
    const float* c1b      = (const float*)d_in[22];
    const float* c2w      = (const float*)d_in[23];
    const float* c2b      = (const float*)d_in[24];
    const float* c3w      = (const float*)d_in[25];
    const float* c3b      = (const float*)d_in[26];
    float* out = (float*)d_out;
    float* ws  = (float*)d_ws;

    float* Cws   = ws + WS_C;
    float* Wt    = ws + WS_WT;
    float* bias2 = ws + WS_B2;
    float* clsin = ws + WS_CLS;
    float* g0buf = ws + WS_G0;
    float* qpB   = ws + WS_QPB;
    float* basB  = ws + WS_BAS;
    float* accP  = ws + WS_ACCP;
    float* sPb   = ws + WS_SP;
    float* gibuf = ws + WS_GI;

    // --- score-polynomial coefficients (parallel pipeline) ---
    k_basis<<<1, 128, 0, stream>>>(per_w, per_b, basB);
    k_qp<<<128, 128, 0, stream>>>(qtimes, lin_w, lin_b, per_w, per_b, wq, bq, qpB);
    k_qtc<<<128, 128, 0, stream>>>(qpB, wk, bk, lin_w, lin_b, basB, Cws);

    k_fuse<<<99, 256, 0, stream>>>(g0_wih, wo, bo, g0_bih, Wt, bias2);
    k_attn<<<256, 512, 0, stream>>>(x, tsteps, Cws, accP, sPb);

    // layer 0: gi = att @ Wt^T + bias2 (att assembled in-GEMM from accP/sP)
    k_gemm_att<<<dim3(128, 12), 256, 0, stream>>>(accP, sPb, Wt, bias2, gibuf);
    k_gru<<<128, 512, 0, stream>>>(gibuf, g0_whh, g0_bhh, g0buf, nullptr);

    // layer 1: gi = g0 @ wih^T + bih   (A: 8192x256, B: 768x256)
    k_gemm_nt<<<dim3(128, 12), 256, 0, stream>>>(g0buf, g1_wih, g1_bih, gibuf, 768, 256);
    k_gru<<<128, 512, 0, stream>>>(gibuf, g1_whh, g1_bhh, nullptr, clsin);

    k_cls<<<64, 256, 0, stream>>>(clsin, c1w, c1b, c2w, c2b, c3w, c3b, out);
}

// Round 5
// 331.678 us; speedup vs baseline: 2.3313x; 1.0919x over previous
//
#include <hip/hip_runtime.h>
#include <math.h>

#define Bn   64
#define Ln   4096
#define LQn  128
#define Dn   32
#define ETn  128
#define Hn   128
#define G3n  384
#define NDEG 12
#define GCHUNK 8

typedef __attribute__((ext_vector_type(2))) float f32x2;

// DPP helpers (VALU cross-lane, no LDS pipe)
#define DPPF(x, ctrl) __int_as_float(__builtin_amdgcn_update_dpp(0, __float_as_int(x), (ctrl), 0xF, 0xF, true))
#define QP_XOR1 0xB1   // quad_perm [1,0,3,2]
#define QP_XOR2 0x4E   // quad_perm [2,3,0,1]
#define QP_B0   0x00
#define QP_B1   0x55
#define QP_B2   0xAA
#define QP_B3   0xFF

// odd sin polynomial, |x| <= ~0.5, err < 5e-9
__device__ __forceinline__ float sin_poly(float x) {
    const float x2 = x * x;
    float r = -1.9841270114e-04f;
    r = fmaf(r, x2,  8.3333337680e-03f);
    r = fmaf(r, x2, -1.6666667163e-01f);
    return fmaf(r * x2, x, x);
}
// even cos polynomial, |x| <= ~0.5, err < 3e-10
__device__ __forceinline__ float cos_poly(float x) {
    const float x2 = x * x;
    float r =  2.4801587642e-05f;
    r = fmaf(r, x2, -1.3888888899e-03f);
    r = fmaf(r, x2,  4.1666667908e-02f);
    r = fmaf(r, x2, -5.0000000000e-01f);
    return fmaf(r, x2, 1.0f);
}

// ---- workspace layout (float offsets) ----
#define WS_C    0                          // 128*12
#define WS_WT   4096                       // 768*32
#define WS_B2   (WS_WT + 768*32)           // 768 (pad 1024)
#define WS_CLS  (WS_B2 + 1024)             // 64*256
#define WS_G0   (WS_CLS + Bn*2*Hn)         // 8192*256  (transient aliases below)
#define WS_GI   (WS_G0 + Bn*LQn*2*Hn)      // 8192*768
// transient aliases inside WS_G0 (dead before the region's next use):
#define WS_QPB  WS_G0                      // 128*128 qp matrix (k_qp -> k_qtc)
#define WS_BAS  (WS_G0 + 16384)            // 12*128 basis     (k_basis -> k_qtc)
#define WS_ACCP WS_G0                      // 4*8192*32 (k_attn -> k_gemm_att)
#define WS_SP   (WS_G0 + 1048576)          // 4*8192

// =================== K1a: basis[d][j] = pw_j^d/d! * phase(pb_j, d) ===================
__global__ __launch_bounds__(128) void k_basis(
    const float* __restrict__ per_w, const float* __restrict__ per_b,
    float* __restrict__ basis)
{
    const int j = threadIdx.x;
    if (j >= ETn - 1) return;
    const float w = per_w[j], b = per_b[j];
    const float sb = sin_poly(b), cb = cos_poly(b);
    float wp = 1.f;
#pragma unroll
    for (int d = 0; d < NDEG; ++d) {
        const float sd = ((d & 3) == 0) ? sb : ((d & 3) == 1) ? cb : ((d & 3) == 2) ? -sb : -cb;
        basis[d * 128 + j] = wp * sd;
        wp *= w / (float)(d + 1);
    }
}

// =================== K1b: qp[q][e] = sum_i qe[q][i]*wq[i][e] + bq[e] ===================
__global__ __launch_bounds__(128) void k_qp(
    const float* __restrict__ qtimes, const float* __restrict__ lin_w,
    const float* __restrict__ lin_b, const float* __restrict__ per_w,
    const float* __restrict__ per_b, const float* __restrict__ wq,
    const float* __restrict__ bq, float* __restrict__ qp)
{
    __shared__ float qe[ETn];
    const int q = blockIdx.x, e = threadIdx.x;
    const float t = qtimes[q];
    qe[e] = (e == 0) ? fmaf(t, lin_w[0], lin_b[0])
                     : sin_poly(fmaf(t, per_w[e - 1], per_b[e - 1]));
    __syncthreads();
    float a = bq[e];
#pragma unroll 16
    for (int i = 0; i < ETn; ++i) a = fmaf(qe[i], wq[i * ETn + e], a);
    qp[q * ETn + e] = a;
}

// =================== K1c: qt + coefficients C[q][d] ===================
__global__ __launch_bounds__(128) void k_qtc(
    const float* __restrict__ qp, const float* __restrict__ wk,
    const float* __restrict__ bk, const float* __restrict__ lin_w,
    const float* __restrict__ lin_b, const float* __restrict__ basis,
    float* __restrict__ C)
{
    __shared__ float qp_l[ETn], qt_l[ETn], red[96], qbk_red[32];
    const int q = blockIdx.x, tid = threadIdx.x;
    qp_l[tid] = qp[q * ETn + tid];
    __syncthreads();
    {
        const float4* wk4 = (const float4*)(wk + (size_t)tid * ETn);
        const float4* qp4 = (const float4*)qp_l;
        float a = 0.f;
#pragma unroll
        for (int k = 0; k < 32; ++k) {
            const float4 w4 = wk4[k], p4 = qp4[k];
            a += w4.x * p4.x + w4.y * p4.y + w4.z * p4.z + w4.w * p4.w;
        }
        qt_l[tid] = a;
    }
    __syncthreads();
    if (tid < 96) {
        const int d = tid >> 3, g = tid & 7;
        float p = 0.f;
        for (int j = g; j < ETn - 1; j += 8) p = fmaf(qt_l[j + 1], basis[d * 128 + j], p);
        red[tid] = p;
    } else {
        const int g2 = tid - 96;
        float p = 0.f;
#pragma unroll
        for (int k = 0; k < 4; ++k) p = fmaf(qp_l[g2 + 32 * k], bk[g2 + 32 * k], p);
        qbk_red[g2] = p;
    }
    __syncthreads();
    if (tid < NDEG) {
        const int d = tid;
        float s = red[d * 8 + 0] + red[d * 8 + 1] + red[d * 8 + 2] + red[d * 8 + 3]
                + red[d * 8 + 4] + red[d * 8 + 5] + red[d * 8 + 6] + red[d * 8 + 7];
        if (d == 0) {
            float qbk = 0.f;
#pragma unroll
            for (int k = 0; k < 32; ++k) qbk += qbk_red[k];
            s += qt_l[0] * lin_b[0] + qbk;
        }
        if (d == 1) s += qt_l[0] * lin_w[0];
        C[q * NDEG + d] = s * 0.08838834764831845f;   // 1/sqrt(128)
    }
}

// =================== K1d: fold wo (+bo) into layer-0 wih ===================
__global__ __launch_bounds__(256) void k_fuse(
    const float* __restrict__ wih, const float* __restrict__ wo,
    const float* __restrict__ bo, const float* __restrict__ bih,
    float* __restrict__ Wt, float* __restrict__ bias2)
{
    const int t = blockIdx.x * 256 + threadIdx.x;
    if (t < 768 * 32) {
        const int o = t >> 5, d = t & 31;
        const float* wr = wih + (size_t)o * 128;
        const float* wc = wo + (size_t)d * 128;
        float a = 0.f;
        for (int h = 0; h < 128; ++h) a += wr[h] * wc[h];
        Wt[t] = a;
    } else if (t < 768 * 33) {
        const int o = t - 768 * 32;
        const float* wr = wih + (size_t)o * 128;
        float a = bih[o];
        for (int h = 0; h < 128; ++h) a += bo[h] * wr[h];
        bias2[o] = a;
    }
}

// =================== K2: attention, unnormalized (no max-sub: |score| <= ~6) ===================
#define ACC8(m, pv) \
    acc[m][0].x = fmaf(pv, xa.x, acc[m][0].x); acc[m][0].y = fmaf(pv, xa.y, acc[m][0].y); \
    acc[m][0].z = fmaf(pv, xa.z, acc[m][0].z); acc[m][0].w = fmaf(pv, xa.w, acc[m][0].w); \
    acc[m][1].x = fmaf(pv, xb.x, acc[m][1].x); acc[m][1].y = fmaf(pv, xb.y, acc[m][1].y); \
    acc[m][1].z = fmaf(pv, xb.z, acc[m][1].z); acc[m][1].w = fmaf(pv, xb.w, acc[m][1].w);

__global__ __launch_bounds__(512, 2) void k_attn(
    const float* __restrict__ x, const float* __restrict__ tsteps,
    const float* __restrict__ Cc, float* __restrict__ accP, float* __restrict__ sP)
{
    __shared__ float slab[4][128][36];
    const int tid = threadIdx.x;
    const int b = blockIdx.x >> 2, lsplit = blockIdx.x & 3;
    const int i = tid & 3, qt = (tid >> 2) & 31, ls2 = tid >> 7;
    const int qown = 4 * qt + i;

    float c[NDEG];
#pragma unroll
    for (int d = 0; d < NDEG; ++d) c[d] = Cc[qown * NDEG + d];

    const int l0 = lsplit * 1024 + ls2 * 256;
    const float4* tg4 = (const float4*)(tsteps + (size_t)b * Ln + l0);
    const float4* xg  = (const float4*)(x + ((size_t)b * Ln + l0) * Dn);

    float4 acc[4][2];
#pragma unroll
    for (int m = 0; m < 4; ++m)
#pragma unroll
        for (int e = 0; e < 2; ++e) { acc[m][e].x = 0.f; acc[m][e].y = 0.f; acc[m][e].z = 0.f; acc[m][e].w = 0.f; }
    float s_own = 0.f;

    for (int k = 0; k < 64; ++k) {
        const float4 t4 = tg4[k];
#pragma unroll
        for (int jj = 0; jj < 4; ++jj) {
            const float t = (jj == 0) ? t4.x : (jj == 1) ? t4.y : (jj == 2) ? t4.z : t4.w;
            float sc = c[NDEG - 1];
#pragma unroll
            for (int d = NDEG - 2; d >= 0; --d) sc = fmaf(sc, t, c[d]);
            const float pe = __expf(sc);
            s_own += pe;
            const float p0 = DPPF(pe, QP_B0);
            const float p1 = DPPF(pe, QP_B1);
            const float p2 = DPPF(pe, QP_B2);
            const float p3 = DPPF(pe, QP_B3);
            const int lrow = (k * 4 + jj) * 8;
            const float4 xa = xg[lrow + 2 * i];
            const float4 xb = xg[lrow + 2 * i + 1];
            ACC8(0, p0) ACC8(1, p1) ACC8(2, p2) ACC8(3, p3)
        }
    }
#pragma unroll
    for (int m = 0; m < 4; ++m) {
        *(float4*)&slab[ls2][4 * qt + m][8 * i]     = acc[m][0];
        *(float4*)&slab[ls2][4 * qt + m][8 * i + 4] = acc[m][1];
    }
    slab[ls2][qown][32] = s_own;
    __syncthreads();
    const int q = tid & 127, part = tid >> 7;
#pragma unroll
    for (int j = 0; j < 2; ++j) {
        const int off = (part * 2 + j) * 4;
        float4 r  = *(float4*)&slab[0][q][off];
        float4 r1 = *(float4*)&slab[1][q][off];
        float4 r2 = *(float4*)&slab[2][q][off];
        float4 r3 = *(float4*)&slab[3][q][off];
        r.x += r1.x + r2.x + r3.x; r.y += r1.y + r2.y + r3.y;
        r.z += r1.z + r2.z + r3.z; r.w += r1.w + r2.w + r3.w;
        *(float4*)&accP[((((size_t)lsplit * Bn + b) * LQn + q) * 32) + off] = r;
    }
    if (part == 0) {
        sP[((size_t)lsplit * Bn + b) * LQn + q] =
            slab[0][q][32] + slab[1][q][32] + slab[2][q][32] + slab[3][q][32];
    }
}

// =================== K3a: GEMM layer-0: A = (sum_ls accP)/(sum_ls sP), K=32 ===================
__global__ __launch_bounds__(256) void k_gemm_att(
    const float* __restrict__ accP, const float* __restrict__ sP,
    const float* __restrict__ Bm, const float* __restrict__ bias,
    float* __restrict__ Cm)
{
    __shared__ float4 A_l[64 * 8];
    __shared__ float4 B_l[64 * 8];
    const int tid = threadIdx.x;
    const int m0 = blockIdx.x * 64, n0 = blockIdx.y * 64;
    const int r0 = (tid >> 4) << 2, c0 = (tid & 15) << 2;
    float acc[4][4] = {};
    const float4* Ag = (const float4*)accP;
    const float4* Bg = (const float4*)Bm;

#pragma unroll
    for (int w = 0; w < 2; ++w) {
        const int idx = tid + w * 256;
        const int row = idx >> 3, c4 = idx & 7;
        const int sc = (c4 + row + (row >> 2)) & 7;
        const int m = m0 + row;
        float4 a0 = Ag[(size_t)m * 8 + c4];
        float4 a1 = Ag[((size_t)8192  + m) * 8 + c4];
        float4 a2 = Ag[((size_t)16384 + m) * 8 + c4];
        float4 a3 = Ag[((size_t)24576 + m) * 8 + c4];
        const float inv = 1.f / (sP[m] + sP[8192 + m] + sP[16384 + m] + sP[24576 + m]);
        float4 av;
        av.x = (a0.x + a1.x + a2.x + a3.x) * inv;
        av.y = (a0.y + a1.y + a2.y + a3.y) * inv;
        av.z = (a0.z + a1.z + a2.z + a3.z) * inv;
        av.w = (a0.w + a1.w + a2.w + a3.w) * inv;
        A_l[row * 8 + sc] = av;
        B_l[row * 8 + sc] = Bg[(size_t)(n0 + row) * 8 + c4];
    }
    __syncthreads();
#pragma unroll
    for (int k4 = 0; k4 < 8; ++k4) {
        float4 av[4], bv[4];
#pragma unroll
        for (int j = 0; j < 4; ++j) {
            const int ra = r0 + j;
            av[j] = A_l[ra * 8 + ((k4 + ra + (ra >> 2)) & 7)];
        }
#pragma unroll
        for (int j = 0; j < 4; ++j) {
            const int rb = c0 + j;
            bv[j] = B_l[rb * 8 + ((k4 + rb + (rb >> 2)) & 7)];
        }
#pragma unroll
        for (int ri = 0; ri < 4; ++ri)
#pragma unroll
            for (int ci = 0; ci < 4; ++ci)
                acc[ri][ci] += av[ri].x * bv[ci].x + av[ri].y * bv[ci].y
                             + av[ri].z * bv[ci].z + av[ri].w * bv[ci].w;
    }
#pragma unroll
    for (int ri = 0; ri < 4; ++ri) {
        float4 o4;
        o4.x = acc[ri][0] + bias[n0 + c0 + 0];
        o4.y = acc[ri][1] + bias[n0 + c0 + 1];
        o4.z = acc[ri][2] + bias[n0 + c0 + 2];
        o4.w = acc[ri][3] + bias[n0 + c0 + 3];
        *(float4*)&Cm[(size_t)(m0 + r0 + ri) * 768 + n0 + c0] = o4;
    }
}

// =================== K3b: tiled f32 GEMM  C = A(MxK) @ B(NxK)^T + bias ===================
__global__ __launch_bounds__(256) void k_gemm_nt(
    const float* __restrict__ A, const float* __restrict__ Bm,
    const float* __restrict__ bias, float* __restrict__ Cm,
    int N, int K)
{
    __shared__ float4 A_l[64 * 8];
    __shared__ float4 B_l[64 * 8];
    const int tid = threadIdx.x;
    const int m0 = blockIdx.x * 64, n0 = blockIdx.y * 64;
    const int r0 = (tid >> 4) << 2, c0 = (tid & 15) << 2;
    const int K4 = K >> 2;
    float acc[4][4] = {};
    const float4* Ag = (const float4*)A;
    const float4* Bg = (const float4*)Bm;

    for (int k0 = 0; k0 < K4; k0 += 8) {
        __syncthreads();
#pragma unroll
        for (int w = 0; w < 2; ++w) {
            const int idx = tid + w * 256;
            const int row = idx >> 3, c4 = idx & 7;
            const int sc = (c4 + row + (row >> 2)) & 7;
            A_l[row * 8 + sc] = Ag[(size_t)(m0 + row) * K4 + k0 + c4];
            B_l[row * 8 + sc] = Bg[(size_t)(n0 + row) * K4 + k0 + c4];
        }
        __syncthreads();
#pragma unroll
        for (int k4 = 0; k4 < 8; ++k4) {
            float4 av[4], bv[4];
#pragma unroll
            for (int j = 0; j < 4; ++j) {
                const int ra = r0 + j;
                av[j] = A_l[ra * 8 + ((k4 + ra + (ra >> 2)) & 7)];
            }
#pragma unroll
            for (int j = 0; j < 4; ++j) {
                const int rb = c0 + j;
                bv[j] = B_l[rb * 8 + ((k4 + rb + (rb >> 2)) & 7)];
            }
#pragma unroll
            for (int ri = 0; ri < 4; ++ri)
#pragma unroll
                for (int ci = 0; ci < 4; ++ci)
                    acc[ri][ci] += av[ri].x * bv[ci].x + av[ri].y * bv[ci].y
                                 + av[ri].z * bv[ci].z + av[ri].w * bv[ci].w;
        }
    }
#pragma unroll
    for (int ri = 0; ri < 4; ++ri) {
        float4 o4;
        o4.x = acc[ri][0] + bias[n0 + c0 + 0];
        o4.y = acc[ri][1] + bias[n0 + c0 + 1];
        o4.z = acc[ri][2] + bias[n0 + c0 + 2];
        o4.w = acc[ri][3] + bias[n0 + c0 + 3];
        *(float4*)&Cm[(size_t)(m0 + r0 + ri) * N + n0 + c0] = o4;
    }
}

// =================== K4: GRU recurrence — chunked gi prefetch, batched stores ===================
// 512 threads: (j = tid>>2, q = tid&3 = 32-wide h-slice). One block per (b,dir).
// gi double-buffered in registers (2 x GCHUNK), issue->consume distance = 8 steps.
__global__ __launch_bounds__(512, 2) void k_gru(
    const float* __restrict__ gi, const float* __restrict__ whh,
    const float* __restrict__ bhh, float* __restrict__ seq_out,
    float* __restrict__ final_out)
{
    __shared__ float h_l[2][4 * 36];
    const int tid = threadIdx.x;
    const int b = blockIdx.x >> 1, dir = blockIdx.x & 1;
    const int j = tid >> 2, q = tid & 3;

    f32x2 wr[16], wz[16], wn[16];
    {
        const float* wb = whh + ((size_t)dir * G3n + j) * Hn + 32 * q;
        const f32x2* p0 = (const f32x2*)(wb);
        const f32x2* p1 = (const f32x2*)(wb + (size_t)128 * Hn);
        const f32x2* p2 = (const f32x2*)(wb + (size_t)256 * Hn);
#pragma unroll
        for (int k = 0; k < 16; ++k) { wr[k] = p0[k]; wz[k] = p1[k]; wn[k] = p2[k]; }
    }
    const float bhr = bhh[dir * G3n + j];
    const float bhz = bhh[dir * G3n + 128 + j];
    const float bhn = bhh[dir * G3n + 256 + j];

    if (tid < 144) h_l[0][tid] = 0.f;
    __syncthreads();

    // per-thread gi pointer: element (l) at gptr + step*sstride
    const long sstride = dir ? -768 : 768;
    const float* gptr = gi + (size_t)b * LQn * 768 + dir * G3n + q * Hn + j
                        + (size_t)(dir ? LQn - 1 : 0) * 768;
    const int hslot = (j >> 5) * 36 + (j & 31);
    const bool ldq = (q < 3);
    const bool stq = (q == 3);

    int cur = 0;
    float hlast = 0.f;

    // step lambda: consumes gi for this step, returns new h for unit j
    auto gstep = [&](const float gi_cur) -> float {
        const float4* hq = (const float4*)(&h_l[cur][q * 36]);
        f32x2 ar = {0.f, 0.f}, az = {0.f, 0.f}, an = {0.f, 0.f};
        f32x2 br = {0.f, 0.f}, bz = {0.f, 0.f}, bn = {0.f, 0.f};
#pragma unroll
        for (int cc = 0; cc < 4; ++cc) {
            float4 hv = hq[cc];
            f32x2 h01; h01.x = hv.x; h01.y = hv.y;
            f32x2 h23; h23.x = hv.z; h23.y = hv.w;
            asm("v_pk_fma_f32 %0, %1, %2, %0" : "+v"(ar) : "v"(wr[2 * cc]),     "v"(h01));
            asm("v_pk_fma_f32 %0, %1, %2, %0" : "+v"(az) : "v"(wz[2 * cc]),     "v"(h01));
            asm("v_pk_fma_f32 %0, %1, %2, %0" : "+v"(an) : "v"(wn[2 * cc]),     "v"(h01));
            asm("v_pk_fma_f32 %0, %1, %2, %0" : "+v"(ar) : "v"(wr[2 * cc + 1]), "v"(h23));
            asm("v_pk_fma_f32 %0, %1, %2, %0" : "+v"(az) : "v"(wz[2 * cc + 1]), "v"(h23));
            asm("v_pk_fma_f32 %0, %1, %2, %0" : "+v"(an) : "v"(wn[2 * cc + 1]), "v"(h23));
        }
#pragma unroll
        for (int cc = 4; cc < 8; ++cc) {
            float4 hv = hq[cc];
            f32x2 h01; h01.x = hv.x; h01.y = hv.y;
            f32x2 h23; h23.x = hv.z; h23.y = hv.w;
            asm("v_pk_fma_f32 %0, %1, %2, %0" : "+v"(br) : "v"(wr[2 * cc]),     "v"(h01));
            asm("v_pk_fma_f32 %0, %1, %2, %0" : "+v"(bz) : "v"(wz[2 * cc]),     "v"(h01));
            asm("v_pk_fma_f32 %0, %1, %2, %0" : "+v"(bn) : "v"(wn[2 * cc]),     "v"(h01));
            asm("v_pk_fma_f32 %0, %1, %2, %0" : "+v"(br) : "v"(wr[2 * cc + 1]), "v"(h23));
            asm("v_pk_fma_f32 %0, %1, %2, %0" : "+v"(bz) : "v"(wz[2 * cc + 1]), "v"(h23));
            asm("v_pk_fma_f32 %0, %1, %2, %0" : "+v"(bn) : "v"(wn[2 * cc + 1]), "v"(h23));
        }
        float sr = (ar.x + br.x) + (ar.y + br.y);
        float sz = (az.x + bz.x) + (az.y + bz.y);
        float sn = (an.x + bn.x) + (an.y + bn.y);
        sr += DPPF(sr, QP_XOR1); sr += DPPF(sr, QP_XOR2);
        sz += DPPF(sz, QP_XOR1); sz += DPPF(sz, QP_XOR2);
        sn += DPPF(sn, QP_XOR1); sn += DPPF(sn, QP_XOR2);
        const float gir = DPPF(gi_cur, QP_B0);
        const float giz = DPPF(gi_cur, QP_B1);
        const float gin = DPPF(gi_cur, QP_B2);
        const float hold = h_l[cur][hslot];
        const float r = 1.f / (1.f + __expf(-(gir + sr + bhr)));
        const float z = 1.f / (1.f + __expf(-(giz + sz + bhz)));
        const float nx = gin + r * (sn + bhn);
        const float n = 1.f - 2.f / (1.f + __expf(2.f * nx));   // tanh
        const float hn = n + z * (hold - n);
        if (q == 0) h_l[cur ^ 1][hslot] = hn;
        cur ^= 1;
        __syncthreads();
        return hn;
    };

    float giA[GCHUNK], giB[GCHUNK], hs[GCHUNK];
#pragma unroll
    for (int s = 0; s < GCHUNK; ++s) giA[s] = ldq ? gptr[(long)s * sstride] : 0.f;
#pragma unroll
    for (int s = 0; s < GCHUNK; ++s) giB[s] = ldq ? gptr[(long)(GCHUNK + s) * sstride] : 0.f;

    const int NCH = LQn / GCHUNK;   // 16
    for (int c = 0; c < NCH; c += 2) {
        // ---- chunk c (giA) ----
#pragma unroll
        for (int s = 0; s < GCHUNK; ++s) hs[s] = gstep(giA[s]);
        if (seq_out && stq) {
#pragma unroll
            for (int s = 0; s < GCHUNK; ++s) {
                const int l = dir ? (LQn - 1 - (c * GCHUNK + s)) : (c * GCHUNK + s);
                seq_out[((size_t)(b * LQn + l)) * (2 * Hn) + dir * Hn + j] = hs[s];
            }
        }
        {
            const int cn = (c + 2 < NCH) ? (c + 2) : (NCH - 1);
#pragma unroll
            for (int s = 0; s < GCHUNK; ++s)
                giA[s] = ldq ? gptr[(long)(cn * GCHUNK + s) * sstride] : 0.f;
        }
        // ---- chunk c+1 (giB) ----
#pragma unroll
        for (int s = 0; s < GCHUNK; ++s) hs[s] = gstep(giB[s]);
        if (seq_out && stq) {
#pragma unroll
            for (int s = 0; s < GCHUNK; ++s) {
                const int l = dir ? (LQn - 1 - ((c + 1) * GCHUNK + s)) : ((c + 1) * GCHUNK + s);
                seq_out[((size_t)(b * LQn + l)) * (2 * Hn) + dir * Hn + j] = hs[s];
            }
        }
        {
            const int cn = (c + 3 < NCH) ? (c + 3) : (NCH - 1);
#pragma unroll
            for (int s = 0; s < GCHUNK; ++s)
                giB[s] = ldq ? gptr[(long)(cn * GCHUNK + s) * sstride] : 0.f;
        }
        hlast = hs[GCHUNK - 1];
    }
    if (final_out && stq) final_out[b * 2 * Hn + dir * Hn + j] = hlast;
}

// =================== K5: classifier MLP ===================
__global__ __launch_bounds__(256) void k_cls(
    const float* __restrict__ cls_in,
    const float* __restrict__ c1w, const float* __restrict__ c1b,
    const float* __restrict__ c2w, const float* __restrict__ c2b,
    const float* __restrict__ c3w, const float* __restrict__ c3b,
    float* __restrict__ out)
{
    __shared__ float ci[256], y1[128], y2[64];
    const int b = blockIdx.x, tid = threadIdx.x;
    ci[tid] = cls_in[b * 256 + tid];
    __syncthreads();
    if (tid < 128) { float a = c1b[tid]; for (int i = 0; i < 256; ++i) a += ci[i] * c1w[i * 128 + tid]; y1[tid] = a; }
    __syncthreads();
    if (tid < 64)  { float a = c2b[tid]; for (int i = 0; i < 128; ++i) a += y1[i] * c2w[i * 64 + tid];  y2[tid] = a; }
    __syncthreads();
    if (tid < 6)   { float a = c3b[tid]; for (int i = 0; i < 64; ++i)  a += y2[i] * c3w[i * 6 + tid];   out[b * 6 + tid] = a; }
}

// =================== launch ===================
extern "C" void kernel_launch(void* const* d_in, const int* in_sizes, int n_in,
                              void* d_out, int out_size, void* d_ws, size_t ws_size,
                              hipStream_t stream)
{
    const float* x        = (const float*)d_in[0];
    const float* tsteps   = (const float*)d_in[1];
    const float* qtimes   = (const float*)d_in[2];
    const float* lin_w    = (const float*)d_in[3];
    const float* lin_b    = (const float*)d_in[4];
    const float* per_w    = (const float*)d_in[5];
    const float* per_b    = (const float*)d_in[6];
    const float* wq       = (const float*)d_in[7];
    const float* bq       = (const float*)d_in[8];
    const float* wk       = (const float*)d_in[9];
    const float* bk       = (const float*)d_in[10];
    const float* wo       = (const float*)d_in[11];
    const float* bo       = (const float*)d_in[12];
    const float* g0_wih   = (const float*)d_in[13];
    const float* g0_whh   = (const float*)d_in[14];
    const float* g0_bih   = (const float*)d_in[15];
    const float* g0_bhh   = (const float*)d_in[16];
    const float* g1_wih   = (const float*)d_in[17];
    const float* g1_whh   = (const float*)d_in[18];
    const float* g1_bih   = (const float*)d_in[19];
    const float* g1_bhh   = (const float*)d_in[20];
    const float* c1w      = (const float*)d_in[21];
    const float* c1b      = (const float*)d_in[22];
    const float* c2w      = (const float*)d_in[23];
    const float* c2b      = (const float*)d_in[24];
    const float* c3w      = (const float*)d_in[25];
    const float* c3b      = (const float*)d_in[26];
    float* out = (float*)d_out;
    float* ws  = (float*)d_ws;

    float* Cws   = ws + WS_C;
    float* Wt    = ws + WS_WT;
    float* bias2 = ws + WS_B2;
    float* clsin = ws + WS_CLS;
    float* g0buf = ws + WS_G0;
    float* qpB   = ws + WS_QPB;
    float* basB  = ws + WS_BAS;
    float* accP  = ws + WS_ACCP;
    float* sPb   = ws + WS_SP;
    float* gibuf = ws + WS_GI;

    // --- score-polynomial coefficients (parallel pipeline) ---
    k_basis<<<1, 128, 0, stream>>>(per_w, per_b, basB);
    k_qp<<<128, 128, 0, stream>>>(qtimes, lin_w, lin_b, per_w, per_b, wq, bq, qpB);
    k_qtc<<<128, 128, 0, stream>>>(qpB, wk, bk, lin_w, lin_b, basB, Cws);

    k_fuse<<<99, 256, 0, stream>>>(g0_wih, wo, bo, g0_bih, Wt, bias2);
    k_attn<<<256, 512, 0, stream>>>(x, tsteps, Cws, accP, sPb);

    // layer 0: gi = att @ Wt^T + bias2 (att assembled in-GEMM from accP/sP)
    k_gemm_att<<<dim3(128, 12), 256, 0, stream>>>(accP, sPb, Wt, bias2, gibuf);
    k_gru<<<128, 512, 0, stream>>>(gibuf, g0_whh, g0_bhh, g0buf, nullptr);

    // layer 1: gi = g0 @ wih^T + bih   (A: 8192x256, B: 768x256)
    k_gemm_nt<<<dim3(128, 12), 256, 0, stream>>>(g0buf, g1_wih, g1_bih, gibuf, 768, 256);
    k_gru<<<128, 512, 0, stream>>>(gibuf, g1_whh, g1_bhh, nullptr, clsin);

    k_cls<<<64, 256, 0, stream>>>(clsin, c1w, c1b, c2w, c2b, c3w, c3b, out);
}

// Round 6
// 325.149 us; speedup vs baseline: 2.3781x; 1.0201x over previous
//
#include <hip/hip_runtime.h>
#include <math.h>

#define Bn   64
#define Ln   4096
#define LQn  128
#define Dn   32
#define ETn  128
#define Hn   128
#define G3n  384
#define NDEG 12

typedef __attribute__((ext_vector_type(2))) float f32x2;

// DPP helpers (VALU cross-lane, no LDS pipe)
#define DPPF(x, ctrl) __int_as_float(__builtin_amdgcn_update_dpp(0, __float_as_int(x), (ctrl), 0xF, 0xF, true))
#define QP_XOR1 0xB1   // quad_perm [1,0,3,2]
#define QP_XOR2 0x4E   // quad_perm [2,3,0,1]
#define QP_B0   0x00
#define QP_B1   0x55
#define QP_B2   0xAA
#define QP_B3   0xFF

// odd sin polynomial, |x| <= ~0.5, err < 5e-9
__device__ __forceinline__ float sin_poly(float x) {
    const float x2 = x * x;
    float r = -1.9841270114e-04f;
    r = fmaf(r, x2,  8.3333337680e-03f);
    r = fmaf(r, x2, -1.6666667163e-01f);
    return fmaf(r * x2, x, x);
}
// even cos polynomial, |x| <= ~0.5, err < 3e-10
__device__ __forceinline__ float cos_poly(float x) {
    const float x2 = x * x;
    float r =  2.4801587642e-05f;
    r = fmaf(r, x2, -1.3888888899e-03f);
    r = fmaf(r, x2,  4.1666667908e-02f);
    r = fmaf(r, x2, -5.0000000000e-01f);
    return fmaf(r, x2, 1.0f);
}

// ---- workspace layout (float offsets) ----
#define WS_C    0                          // 128*12
#define WS_WT   4096                       // 768*32
#define WS_B2   (WS_WT + 768*32)           // 768 (pad 1024)
#define WS_CLS  (WS_B2 + 1024)             // 64*256
#define WS_G0   (WS_CLS + Bn*2*Hn)         // 8192*256  (transient aliases below)
#define WS_GI   (WS_G0 + Bn*LQn*2*Hn)      // 8192*768
// transient aliases inside WS_G0 (dead before the region's next use):
#define WS_QPB  WS_G0                      // 128*128 qp matrix (k_qp -> k_qtc)
#define WS_BAS  (WS_G0 + 16384)            // 12*128 basis     (k_basis -> k_qtc)
#define WS_ACCP WS_G0                      // 4*8192*32 (k_attn -> k_gemm_att)
#define WS_SP   (WS_G0 + 1048576)          // 4*8192

// =================== K1a: basis[d][j] = pw_j^d/d! * phase(pb_j, d) ===================
__global__ __launch_bounds__(128) void k_basis(
    const float* __restrict__ per_w, const float* __restrict__ per_b,
    float* __restrict__ basis)
{
    const int j = threadIdx.x;
    if (j >= ETn - 1) return;
    const float w = per_w[j], b = per_b[j];
    const float sb = sin_poly(b), cb = cos_poly(b);
    float wp = 1.f;
#pragma unroll
    for (int d = 0; d < NDEG; ++d) {
        const float sd = ((d & 3) == 0) ? sb : ((d & 3) == 1) ? cb : ((d & 3) == 2) ? -sb : -cb;
        basis[d * 128 + j] = wp * sd;
        wp *= w / (float)(d + 1);
    }
}

// =================== K1b: qp[q][e] = sum_i qe[q][i]*wq[i][e] + bq[e] ===================
__global__ __launch_bounds__(128) void k_qp(
    const float* __restrict__ qtimes, const float* __restrict__ lin_w,
    const float* __restrict__ lin_b, const float* __restrict__ per_w,
    const float* __restrict__ per_b, const float* __restrict__ wq,
    const float* __restrict__ bq, float* __restrict__ qp)
{
    __shared__ float qe[ETn];
    const int q = blockIdx.x, e = threadIdx.x;
    const float t = qtimes[q];
    qe[e] = (e == 0) ? fmaf(t, lin_w[0], lin_b[0])
                     : sin_poly(fmaf(t, per_w[e - 1], per_b[e - 1]));
    __syncthreads();
    float a = bq[e];
#pragma unroll 16
    for (int i = 0; i < ETn; ++i) a = fmaf(qe[i], wq[i * ETn + e], a);
    qp[q * ETn + e] = a;
}

// =================== K1c: qt + coefficients C[q][d] ===================
__global__ __launch_bounds__(128) void k_qtc(
    const float* __restrict__ qp, const float* __restrict__ wk,
    const float* __restrict__ bk, const float* __restrict__ lin_w,
    const float* __restrict__ lin_b, const float* __restrict__ basis,
    float* __restrict__ C)
{
    __shared__ float qp_l[ETn], qt_l[ETn], red[96], qbk_red[32];
    const int q = blockIdx.x, tid = threadIdx.x;
    qp_l[tid] = qp[q * ETn + tid];
    __syncthreads();
    {
        const float4* wk4 = (const float4*)(wk + (size_t)tid * ETn);
        const float4* qp4 = (const float4*)qp_l;
        float a = 0.f;
#pragma unroll
        for (int k = 0; k < 32; ++k) {
            const float4 w4 = wk4[k], p4 = qp4[k];
            a += w4.x * p4.x + w4.y * p4.y + w4.z * p4.z + w4.w * p4.w;
        }
        qt_l[tid] = a;
    }
    __syncthreads();
    if (tid < 96) {
        const int d = tid >> 3, g = tid & 7;
        float p = 0.f;
        for (int j = g; j < ETn - 1; j += 8) p = fmaf(qt_l[j + 1], basis[d * 128 + j], p);
        red[tid] = p;
    } else {
        const int g2 = tid - 96;
        float p = 0.f;
#pragma unroll
        for (int k = 0; k < 4; ++k) p = fmaf(qp_l[g2 + 32 * k], bk[g2 + 32 * k], p);
        qbk_red[g2] = p;
    }
    __syncthreads();
    if (tid < NDEG) {
        const int d = tid;
        float s = red[d * 8 + 0] + red[d * 8 + 1] + red[d * 8 + 2] + red[d * 8 + 3]
                + red[d * 8 + 4] + red[d * 8 + 5] + red[d * 8 + 6] + red[d * 8 + 7];
        if (d == 0) {
            float qbk = 0.f;
#pragma unroll
            for (int k = 0; k < 32; ++k) qbk += qbk_red[k];
            s += qt_l[0] * lin_b[0] + qbk;
        }
        if (d == 1) s += qt_l[0] * lin_w[0];
        C[q * NDEG + d] = s * 0.08838834764831845f;   // 1/sqrt(128)
    }
}

// =================== K1d: fold wo (+bo) into layer-0 wih ===================
__global__ __launch_bounds__(256) void k_fuse(
    const float* __restrict__ wih, const float* __restrict__ wo,
    const float* __restrict__ bo, const float* __restrict__ bih,
    float* __restrict__ Wt, float* __restrict__ bias2)
{
    const int t = blockIdx.x * 256 + threadIdx.x;
    if (t < 768 * 32) {
        const int o = t >> 5, d = t & 31;
        const float* wr = wih + (size_t)o * 128;
        const float* wc = wo + (size_t)d * 128;
        float a = 0.f;
        for (int h = 0; h < 128; ++h) a += wr[h] * wc[h];
        Wt[t] = a;
    } else if (t < 768 * 33) {
        const int o = t - 768 * 32;
        const float* wr = wih + (size_t)o * 128;
        float a = bih[o];
        for (int h = 0; h < 128; ++h) a += bo[h] * wr[h];
        bias2[o] = a;
    }
}

// =================== K2: attention, unnormalized (no max-sub: |score| <= ~6) ===================
#define ACC8(m, pv) \
    acc[m][0].x = fmaf(pv, xa.x, acc[m][0].x); acc[m][0].y = fmaf(pv, xa.y, acc[m][0].y); \
    acc[m][0].z = fmaf(pv, xa.z, acc[m][0].z); acc[m][0].w = fmaf(pv, xa.w, acc[m][0].w); \
    acc[m][1].x = fmaf(pv, xb.x, acc[m][1].x); acc[m][1].y = fmaf(pv, xb.y, acc[m][1].y); \
    acc[m][1].z = fmaf(pv, xb.z, acc[m][1].z); acc[m][1].w = fmaf(pv, xb.w, acc[m][1].w);

__global__ __launch_bounds__(512, 2) void k_attn(
    const float* __restrict__ x, const float* __restrict__ tsteps,
    const float* __restrict__ Cc, float* __restrict__ accP, float* __restrict__ sP)
{
    __shared__ float slab[4][128][36];
    const int tid = threadIdx.x;
    const int b = blockIdx.x >> 2, lsplit = blockIdx.x & 3;
    const int i = tid & 3, qt = (tid >> 2) & 31, ls2 = tid >> 7;
    const int qown = 4 * qt + i;

    float c[NDEG];
#pragma unroll
    for (int d = 0; d < NDEG; ++d) c[d] = Cc[qown * NDEG + d];

    const int l0 = lsplit * 1024 + ls2 * 256;
    const float4* tg4 = (const float4*)(tsteps + (size_t)b * Ln + l0);
    const float4* xg  = (const float4*)(x + ((size_t)b * Ln + l0) * Dn);

    float4 acc[4][2];
#pragma unroll
    for (int m = 0; m < 4; ++m)
#pragma unroll
        for (int e = 0; e < 2; ++e) { acc[m][e].x = 0.f; acc[m][e].y = 0.f; acc[m][e].z = 0.f; acc[m][e].w = 0.f; }
    float s_own = 0.f;

    for (int k = 0; k < 64; ++k) {
        const float4 t4 = tg4[k];
#pragma unroll
        for (int jj = 0; jj < 4; ++jj) {
            const float t = (jj == 0) ? t4.x : (jj == 1) ? t4.y : (jj == 2) ? t4.z : t4.w;
            float sc = c[NDEG - 1];
#pragma unroll
            for (int d = NDEG - 2; d >= 0; --d) sc = fmaf(sc, t, c[d]);
            const float pe = __expf(sc);
            s_own += pe;
            const float p0 = DPPF(pe, QP_B0);
            const float p1 = DPPF(pe, QP_B1);
            const float p2 = DPPF(pe, QP_B2);
            const float p3 = DPPF(pe, QP_B3);
            const int lrow = (k * 4 + jj) * 8;
            const float4 xa = xg[lrow + 2 * i];
            const float4 xb = xg[lrow + 2 * i + 1];
            ACC8(0, p0) ACC8(1, p1) ACC8(2, p2) ACC8(3, p3)
        }
    }
#pragma unroll
    for (int m = 0; m < 4; ++m) {
        *(float4*)&slab[ls2][4 * qt + m][8 * i]     = acc[m][0];
        *(float4*)&slab[ls2][4 * qt + m][8 * i + 4] = acc[m][1];
    }
    slab[ls2][qown][32] = s_own;
    __syncthreads();
    const int q = tid & 127, part = tid >> 7;
#pragma unroll
    for (int j = 0; j < 2; ++j) {
        const int off = (part * 2 + j) * 4;
        float4 r  = *(float4*)&slab[0][q][off];
        float4 r1 = *(float4*)&slab[1][q][off];
        float4 r2 = *(float4*)&slab[2][q][off];
        float4 r3 = *(float4*)&slab[3][q][off];
        r.x += r1.x + r2.x + r3.x; r.y += r1.y + r2.y + r3.y;
        r.z += r1.z + r2.z + r3.z; r.w += r1.w + r2.w + r3.w;
        *(float4*)&accP[((((size_t)lsplit * Bn + b) * LQn + q) * 32) + off] = r;
    }
    if (part == 0) {
        sP[((size_t)lsplit * Bn + b) * LQn + q] =
            slab[0][q][32] + slab[1][q][32] + slab[2][q][32] + slab[3][q][32];
    }
}

// =================== K3a: GEMM layer-0: A = (sum_ls accP)/(sum_ls sP), K=32 ===================
__global__ __launch_bounds__(256) void k_gemm_att(
    const float* __restrict__ accP, const float* __restrict__ sP,
    const float* __restrict__ Bm, const float* __restrict__ bias,
    float* __restrict__ Cm)
{
    __shared__ float4 A_l[64 * 8];
    __shared__ float4 B_l[64 * 8];
    const int tid = threadIdx.x;
    const int m0 = blockIdx.x * 64, n0 = blockIdx.y * 64;
    const int r0 = (tid >> 4) << 2, c0 = (tid & 15) << 2;
    float acc[4][4] = {};
    const float4* Ag = (const float4*)accP;
    const float4* Bg = (const float4*)Bm;

#pragma unroll
    for (int w = 0; w < 2; ++w) {
        const int idx = tid + w * 256;
        const int row = idx >> 3, c4 = idx & 7;
        const int sc = (c4 + row + (row >> 2)) & 7;
        const int m = m0 + row;
        float4 a0 = Ag[(size_t)m * 8 + c4];
        float4 a1 = Ag[((size_t)8192  + m) * 8 + c4];
        float4 a2 = Ag[((size_t)16384 + m) * 8 + c4];
        float4 a3 = Ag[((size_t)24576 + m) * 8 + c4];
        const float inv = 1.f / (sP[m] + sP[8192 + m] + sP[16384 + m] + sP[24576 + m]);
        float4 av;
        av.x = (a0.x + a1.x + a2.x + a3.x) * inv;
        av.y = (a0.y + a1.y + a2.y + a3.y) * inv;
        av.z = (a0.z + a1.z + a2.z + a3.z) * inv;
        av.w = (a0.w + a1.w + a2.w + a3.w) * inv;
        A_l[row * 8 + sc] = av;
        B_l[row * 8 + sc] = Bg[(size_t)(n0 + row) * 8 + c4];
    }
    __syncthreads();
#pragma unroll
    for (int k4 = 0; k4 < 8; ++k4) {
        float4 av[4], bv[4];
#pragma unroll
        for (int j = 0; j < 4; ++j) {
            const int ra = r0 + j;
            av[j] = A_l[ra * 8 + ((k4 + ra + (ra >> 2)) & 7)];
        }
#pragma unroll
        for (int j = 0; j < 4; ++j) {
            const int rb = c0 + j;
            bv[j] = B_l[rb * 8 + ((k4 + rb + (rb >> 2)) & 7)];
        }
#pragma unroll
        for (int ri = 0; ri < 4; ++ri)
#pragma unroll
            for (int ci = 0; ci < 4; ++ci)
                acc[ri][ci] += av[ri].x * bv[ci].x + av[ri].y * bv[ci].y
                             + av[ri].z * bv[ci].z + av[ri].w * bv[ci].w;
    }
#pragma unroll
    for (int ri = 0; ri < 4; ++ri) {
        float4 o4;
        o4.x = acc[ri][0] + bias[n0 + c0 + 0];
        o4.y = acc[ri][1] + bias[n0 + c0 + 1];
        o4.z = acc[ri][2] + bias[n0 + c0 + 2];
        o4.w = acc[ri][3] + bias[n0 + c0 + 3];
        *(float4*)&Cm[(size_t)(m0 + r0 + ri) * 768 + n0 + c0] = o4;
    }
}

// =================== K3b: tiled f32 GEMM  C = A(MxK) @ B(NxK)^T + bias ===================
__global__ __launch_bounds__(256) void k_gemm_nt(
    const float* __restrict__ A, const float* __restrict__ Bm,
    const float* __restrict__ bias, float* __restrict__ Cm,
    int N, int K)
{
    __shared__ float4 A_l[64 * 8];
    __shared__ float4 B_l[64 * 8];
    const int tid = threadIdx.x;
    const int m0 = blockIdx.x * 64, n0 = blockIdx.y * 64;
    const int r0 = (tid >> 4) << 2, c0 = (tid & 15) << 2;
    const int K4 = K >> 2;
    float acc[4][4] = {};
    const float4* Ag = (const float4*)A;
    const float4* Bg = (const float4*)Bm;

    for (int k0 = 0; k0 < K4; k0 += 8) {
        __syncthreads();
#pragma unroll
        for (int w = 0; w < 2; ++w) {
            const int idx = tid + w * 256;
            const int row = idx >> 3, c4 = idx & 7;
            const int sc = (c4 + row + (row >> 2)) & 7;
            A_l[row * 8 + sc] = Ag[(size_t)(m0 + row) * K4 + k0 + c4];
            B_l[row * 8 + sc] = Bg[(size_t)(n0 + row) * K4 + k0 + c4];
        }
        __syncthreads();
#pragma unroll
        for (int k4 = 0; k4 < 8; ++k4) {
            float4 av[4], bv[4];
#pragma unroll
            for (int j = 0; j < 4; ++j) {
                const int ra = r0 + j;
                av[j] = A_l[ra * 8 + ((k4 + ra + (ra >> 2)) & 7)];
            }
#pragma unroll
            for (int j = 0; j < 4; ++j) {
                const int rb = c0 + j;
                bv[j] = B_l[rb * 8 + ((k4 + rb + (rb >> 2)) & 7)];
            }
#pragma unroll
            for (int ri = 0; ri < 4; ++ri)
#pragma unroll
                for (int ci = 0; ci < 4; ++ci)
                    acc[ri][ci] += av[ri].x * bv[ci].x + av[ri].y * bv[ci].y
                                 + av[ri].z * bv[ci].z + av[ri].w * bv[ci].w;
        }
    }
#pragma unroll
    for (int ri = 0; ri < 4; ++ri) {
        float4 o4;
        o4.x = acc[ri][0] + bias[n0 + c0 + 0];
        o4.y = acc[ri][1] + bias[n0 + c0 + 1];
        o4.z = acc[ri][2] + bias[n0 + c0 + 2];
        o4.w = acc[ri][3] + bias[n0 + c0 + 3];
        *(float4*)&Cm[(size_t)(m0 + r0 + ri) * N + n0 + c0] = o4;
    }
}

// =================== K4: GRU recurrence — 4 waves (1/SIMD), 64-wide slices ===================
// 256 threads: (j = tid>>1 in [0,128), q = tid&1 = 64-wide h-slice). One block per (b,dir).
// Weights in regs (192 VGPR), single-DPP pair reduce, 4-deep gi register ring.
__global__ __launch_bounds__(256, 1) void k_gru(
    const float* __restrict__ gi, const float* __restrict__ whh,
    const float* __restrict__ bhh, float* __restrict__ seq_out,
    float* __restrict__ final_out)
{
    __shared__ float h_l[2][Hn];
    const int tid = threadIdx.x;
    const int b = blockIdx.x >> 1, dir = blockIdx.x & 1;
    const int j = tid >> 1, q = tid & 1;

    // weights: w{r,z,n}[k] = whh[dir][g*128+j][64q + 2k .. +1], k=0..31
    f32x2 wr[32], wz[32], wn[32];
    {
        const float* wb = whh + ((size_t)dir * G3n + j) * Hn + 64 * q;
        const f32x2* p0 = (const f32x2*)(wb);
        const f32x2* p1 = (const f32x2*)(wb + (size_t)128 * Hn);
        const f32x2* p2 = (const f32x2*)(wb + (size_t)256 * Hn);
#pragma unroll
        for (int k = 0; k < 32; ++k) { wr[k] = p0[k]; wz[k] = p1[k]; wn[k] = p2[k]; }
    }
    const float bhr = bhh[dir * G3n + j];
    const float bhz = bhh[dir * G3n + 128 + j];
    const float bhn = bhh[dir * G3n + 256 + j];

    if (tid < Hn) { h_l[0][tid] = 0.f; h_l[1][tid] = 0.f; }
    __syncthreads();

    const long sstride = dir ? -768 : 768;
    const float* gptr = gi + (size_t)b * LQn * 768 + dir * G3n + j
                        + (size_t)(dir ? LQn - 1 : 0) * 768;

    int cur = 0;
    float hlast = 0.f;

    // one GRU step; gi gate values passed in registers
    auto gstep = [&](const float gir, const float giz, const float gin,
                     const int step) {
        const float hold = h_l[cur][j];               // own unit's h (hoisted)
        const float4* hb = (const float4*)(&h_l[cur][q * 64]);
        f32x2 ar = {0.f, 0.f}, az = {0.f, 0.f}, an = {0.f, 0.f};
        f32x2 br = {0.f, 0.f}, bz = {0.f, 0.f}, bn = {0.f, 0.f};
#pragma unroll
        for (int cc = 0; cc < 16; ++cc) {
            float4 hv = hb[cc];
            f32x2 h01; h01.x = hv.x; h01.y = hv.y;
            f32x2 h23; h23.x = hv.z; h23.y = hv.w;
            asm("v_pk_fma_f32 %0, %1, %2, %0" : "+v"(ar) : "v"(wr[2 * cc]),     "v"(h01));
            asm("v_pk_fma_f32 %0, %1, %2, %0" : "+v"(az) : "v"(wz[2 * cc]),     "v"(h01));
            asm("v_pk_fma_f32 %0, %1, %2, %0" : "+v"(an) : "v"(wn[2 * cc]),     "v"(h01));
            asm("v_pk_fma_f32 %0, %1, %2, %0" : "+v"(br) : "v"(wr[2 * cc + 1]), "v"(h23));
            asm("v_pk_fma_f32 %0, %1, %2, %0" : "+v"(bz) : "v"(wz[2 * cc + 1]), "v"(h23));
            asm("v_pk_fma_f32 %0, %1, %2, %0" : "+v"(bn) : "v"(wn[2 * cc + 1]), "v"(h23));
        }
        float sr = (ar.x + br.x) + (ar.y + br.y);
        float sz = (az.x + bz.x) + (az.y + bz.y);
        float sn = (an.x + bn.x) + (an.y + bn.y);
        // single-DPP pair reduce (lanes 2j / 2j+1 live in one quad: xor1)
        sr += DPPF(sr, QP_XOR1);
        sz += DPPF(sz, QP_XOR1);
        sn += DPPF(sn, QP_XOR1);
        const float r = 1.f / (1.f + __expf(-(gir + sr + bhr)));
        const float z = 1.f / (1.f + __expf(-(giz + sz + bhz)));
        const float nx = gin + r * (sn + bhn);
        const float n = 1.f - 2.f / (1.f + __expf(2.f * nx));   // tanh
        const float hn = n + z * (hold - n);
        if (q == 0) {
            h_l[cur ^ 1][j] = hn;
            if (seq_out) {
                const int l = dir ? (LQn - 1 - step) : step;
                seq_out[((size_t)(b * LQn + l)) * (2 * Hn) + dir * Hn + j] = hn;
            }
        }
        hlast = hn;
        cur ^= 1;
        __syncthreads();
    };

    // 4-deep gi register ring: distance issue->consume = 4 steps
    float gA[3], gB[3], gC[3], gD[3];
#define GLD(dst, s) { const long o = (long)(s) * sstride; \
    dst[0] = gptr[o]; dst[1] = gptr[o + 128]; dst[2] = gptr[o + 256]; }
    GLD(gA, 0) GLD(gB, 1) GLD(gC, 2) GLD(gD, 3)
    for (int s0 = 0; s0 < LQn; s0 += 4) {
        gstep(gA[0], gA[1], gA[2], s0);
        { const int sn2 = (s0 + 4 < LQn) ? s0 + 4 : LQn - 1; GLD(gA, sn2) }
        gstep(gB[0], gB[1], gB[2], s0 + 1);
        { const int sn2 = (s0 + 5 < LQn) ? s0 + 5 : LQn - 1; GLD(gB, sn2) }
        gstep(gC[0], gC[1], gC[2], s0 + 2);
        { const int sn2 = (s0 + 6 < LQn) ? s0 + 6 : LQn - 1; GLD(gC, sn2) }
        gstep(gD[0], gD[1], gD[2], s0 + 3);
        { const int sn2 = (s0 + 7 < LQn) ? s0 + 7 : LQn - 1; GLD(gD, sn2) }
    }
#undef GLD
    if (final_out && q == 0) final_out[b * 2 * Hn + dir * Hn + j] = hlast;
}

// =================== K5: classifier MLP ===================
__global__ __launch_bounds__(256) void k_cls(
    const float* __restrict__ cls_in,
    const float* __restrict__ c1w, const float* __restrict__ c1b,
    const float* __restrict__ c2w, const float* __restrict__ c2b,
    const float* __restrict__ c3w, const float* __restrict__ c3b,
    float* __restrict__ out)
{
    __shared__ float ci[256], y1[128], y2[64];
    const int b = blockIdx.x, tid = threadIdx.x;
    ci[tid] = cls_in[b * 256 + tid];
    __syncthreads();
    if (tid < 128) { float a = c1b[tid]; for (int i = 0; i < 256; ++i) a += ci[i] * c1w[i * 128 + tid]; y1[tid] = a; }
    __syncthreads();
    if (tid < 64)  { float a = c2b[tid]; for (int i = 0; i < 128; ++i) a += y1[i] * c2w[i * 64 + tid];  y2[tid] = a; }
    __syncthreads();
    if (tid < 6)   { float a = c3b[tid]; for (int i = 0; i < 64; ++i)  a += y2[i] * c3w[i * 6 + tid];   out[b * 6 + tid] = a; }
}

// =================== launch ===================
extern "C" void kernel_launch(void* const* d_in, const int* in_sizes, int n_in,
                              void* d_out, int out_size, void* d_ws, size_t ws_size,
                              hipStream_t stream)
{
    const float* x        = (const float*)d_in[0];
    const float* tsteps   = (const float*)d_in[1];
    const float* qtimes   = (const float*)d_in[2];
    const float* lin_w    = (const float*)d_in[3];
    const float* lin_b    = (const float*)d_in[4];
    const float* per_w    = (const float*)d_in[5];
    const float* per_b    = (const float*)d_in[6];
    const float* wq       = (const float*)d_in[7];
    const float* bq       = (const float*)d_in[8];
    const float* wk       = (const float*)d_in[9];
    const float* bk       = (const float*)d_in[10];
    const float* wo       = (const float*)d_in[11];
    const float* bo       = (const float*)d_in[12];
    const float* g0_wih   = (const float*)d_in[13];
    const float* g0_whh   = (const float*)d_in[14];
    const float* g0_bih   = (const float*)d_in[15];
    const float* g0_bhh   = (const float*)d_in[16];
    const float* g1_wih   = (const float*)d_in[17];
    const float* g1_whh   = (const float*)d_in[18];
    const float* g1_bih   = (const float*)d_in[19];
    const float* g1_bhh   = (const float*)d_in[20];
    const float* c1w      = (const float*)d_in[21];
    const float* c1b      = (const float*)d_in[22];
    const float* c2w      = (const float*)d_in[23];
    const float* c2b      = (const float*)d_in[24];
    const float* c3w      = (const float*)d_in[25];
    const float* c3b      = (const float*)d_in[26];
    float* out = (float*)d_out;
    float* ws  = (float*)d_ws;

    float* Cws   = ws + WS_C;
    float* Wt    = ws + WS_WT;
    float* bias2 = ws + WS_B2;
    float* clsin = ws + WS_CLS;
    float* g0buf = ws + WS_G0;
    float* qpB   = ws + WS_QPB;
    float* basB  = ws + WS_BAS;
    float* accP  = ws + WS_ACCP;
    float* sPb   = ws + WS_SP;
    float* gibuf = ws + WS_GI;

    // --- score-polynomial coefficients (parallel pipeline) ---
    k_basis<<<1, 128, 0, stream>>>(per_w, per_b, basB);
    k_qp<<<128, 128, 0, stream>>>(qtimes, lin_w, lin_b, per_w, per_b, wq, bq, qpB);
    k_qtc<<<128, 128, 0, stream>>>(qpB, wk, bk, lin_w, lin_b, basB, Cws);

    k_fuse<<<99, 256, 0, stream>>>(g0_wih, wo, bo, g0_bih, Wt, bias2);
    k_attn<<<256, 512, 0, stream>>>(x, tsteps, Cws, accP, sPb);

    // layer 0: gi = att @ Wt^T + bias2 (att assembled in-GEMM from accP/sP)
    k_gemm_att<<<dim3(128, 12), 256, 0, stream>>>(accP, sPb, Wt, bias2, gibuf);
    k_gru<<<128, 256, 0, stream>>>(gibuf, g0_whh, g0_bhh, g0buf, nullptr);

    // layer 1: gi = g0 @ wih^T + bih   (A: 8192x256, B: 768x256)
    k_gemm_nt<<<dim3(128, 12), 256, 0, stream>>>(g0buf, g1_wih, g1_bih, gibuf, 768, 256);
    k_gru<<<128, 256, 0, stream>>>(gibuf, g1_whh, g1_bhh, nullptr, clsin);

    k_cls<<<64, 256, 0, stream>>>(clsin, c1w, c1b, c2w, c2b, c3w, c3b, out);
}